// Round 1
// baseline (1028.792 us; speedup 1.0000x reference)
//
#include <hip/hip_runtime.h>

#define IN_DIM 256
#define HID_DIM 128
#define OUT_DIM 64

// ---------------- preprocessing ----------------

__global__ __launch_bounds__(256) void init_kernel(float* deg, int* cnt, int n) {
    int i = blockIdx.x * 256 + threadIdx.x;
    if (i < n) { deg[i] = 1.0f; cnt[i] = 0; }   // self-loop weight 1 pre-seeded
}

__global__ __launch_bounds__(256) void deg_cnt_kernel(const int* __restrict__ col,
        const float* __restrict__ w, float* deg, int* cnt, int e) {
    int i = blockIdx.x * 256 + threadIdx.x;
    if (i < e) {
        int c = col[i];
        atomicAdd(&deg[c], w[i]);
        atomicAdd(&cnt[c], 1);
    }
}

__global__ __launch_bounds__(256) void dinv_kernel(float* deg, int n) {
    int i = blockIdx.x * 256 + threadIdx.x;
    if (i < n) {
        float d = deg[i];
        deg[i] = d > 0.0f ? rsqrtf(d) : 0.0f;   // deg >= 1 always, but match ref
    }
}

// single-block scan over n counts -> exclusive offsets (+ cursors copy)
__global__ __launch_bounds__(1024) void scan_kernel(const int* __restrict__ cnt,
        int* offsets, int* cursors, int n) {
    __shared__ int s[1024];
    int t = threadIdx.x;
    int chunk = (n + 1023) >> 10;
    int begin = t * chunk; if (begin > n) begin = n;
    int end = begin + chunk; if (end > n) end = n;
    int sum = 0;
    for (int i = begin; i < end; i++) sum += cnt[i];
    s[t] = sum;
    __syncthreads();
    for (int d = 1; d < 1024; d <<= 1) {
        int v = (t >= d) ? s[t - d] : 0;
        __syncthreads();
        s[t] += v;
        __syncthreads();
    }
    int prefix = (t == 0) ? 0 : s[t - 1];
    for (int i = begin; i < end; i++) {
        offsets[i] = prefix;
        cursors[i] = prefix;
        prefix += cnt[i];
    }
    if (t == 1023) offsets[n] = s[1023];
}

__global__ __launch_bounds__(256) void fill_csc_kernel(const int* __restrict__ row,
        const int* __restrict__ col, const float* __restrict__ w,
        const float* __restrict__ dinv, int* cursors,
        int* csc_row, float* csc_norm, int e) {
    int i = blockIdx.x * 256 + threadIdx.x;
    if (i < e) {
        int r = row[i], c = col[i];
        float nrm = dinv[r] * w[i] * dinv[c];
        int p = atomicAdd(&cursors[c], 1);
        csc_row[p] = r;
        csc_norm[p] = nrm;
    }
}

// ---------------- GEMM 1: [N,256] @ [256,128] ----------------
// Block: 256 threads -> 64 nodes x 128 cols. Thread: 4 nodes x 8 cols.
// W1 staged in LDS in two 64KB k-halves.

__global__ __launch_bounds__(256) void gemm1_kernel(const float* __restrict__ x,
        const float* __restrict__ W, float* __restrict__ h, int n) {
    __shared__ float4 sW[4096];                       // 64 KB: 128 k-rows x 128 cols
    const float4* W4 = (const float4*)W;
    int t = threadIdx.x;
    int cg = t & 15;                                  // col group: cols cg*8 .. +7
    int ng = t >> 4;                                  // node group: nodes ng*4 .. +3
    long base = (long)blockIdx.x * 64 + ng * 4;

    float acc[4][8];
#pragma unroll
    for (int i = 0; i < 4; i++)
#pragma unroll
        for (int j = 0; j < 8; j++) acc[i][j] = 0.0f;

    for (int half = 0; half < 2; half++) {
        __syncthreads();
        for (int i = t; i < 4096; i += 256) sW[i] = W4[half * 4096 + i];
        __syncthreads();
        int k0 = half * 128;
        for (int k = 0; k < 128; k += 4) {
            float4 xv[4];
#pragma unroll
            for (int i = 0; i < 4; i++) {
                long r = base + i; if (r > n - 1) r = n - 1;
                xv[i] = *(const float4*)(x + r * IN_DIM + k0 + k);
            }
#pragma unroll
            for (int kk = 0; kk < 4; kk++) {
                float4 w0 = sW[(k + kk) * 32 + cg * 2];
                float4 w1 = sW[(k + kk) * 32 + cg * 2 + 1];
#pragma unroll
                for (int i = 0; i < 4; i++) {
                    float xs = (kk == 0) ? xv[i].x : (kk == 1) ? xv[i].y
                             : (kk == 2) ? xv[i].z : xv[i].w;
                    acc[i][0] += xs * w0.x; acc[i][1] += xs * w0.y;
                    acc[i][2] += xs * w0.z; acc[i][3] += xs * w0.w;
                    acc[i][4] += xs * w1.x; acc[i][5] += xs * w1.y;
                    acc[i][6] += xs * w1.z; acc[i][7] += xs * w1.w;
                }
            }
        }
    }
#pragma unroll
    for (int i = 0; i < 4; i++) {
        long r = base + i;
        if (r < n) {
            float4* dst = (float4*)(h + r * HID_DIM + cg * 8);
            dst[0] = make_float4(acc[i][0], acc[i][1], acc[i][2], acc[i][3]);
            dst[1] = make_float4(acc[i][4], acc[i][5], acc[i][6], acc[i][7]);
        }
    }
}

// ---------------- GEMM 2: [N,128] @ [128,64] ----------------

__global__ __launch_bounds__(256) void gemm2_kernel(const float* __restrict__ a,
        const float* __restrict__ W, float* __restrict__ out, int n) {
    __shared__ float4 sW[2048];                       // 32 KB: 128 x 64
    const float4* W4 = (const float4*)W;
    int t = threadIdx.x;
    int cg = t & 15;                                  // cols cg*4 .. +3
    int ng = t >> 4;                                  // nodes ng*4 .. +3
    long base = (long)blockIdx.x * 64 + ng * 4;
    for (int i = t; i < 2048; i += 256) sW[i] = W4[i];
    __syncthreads();

    float acc[4][4];
#pragma unroll
    for (int i = 0; i < 4; i++)
#pragma unroll
        for (int j = 0; j < 4; j++) acc[i][j] = 0.0f;

    for (int k = 0; k < HID_DIM; k += 4) {
        float4 xv[4];
#pragma unroll
        for (int i = 0; i < 4; i++) {
            long r = base + i; if (r > n - 1) r = n - 1;
            xv[i] = *(const float4*)(a + r * HID_DIM + k);
        }
#pragma unroll
        for (int kk = 0; kk < 4; kk++) {
            float4 wv = sW[(k + kk) * 16 + cg];
#pragma unroll
            for (int i = 0; i < 4; i++) {
                float xs = (kk == 0) ? xv[i].x : (kk == 1) ? xv[i].y
                         : (kk == 2) ? xv[i].z : xv[i].w;
                acc[i][0] += xs * wv.x; acc[i][1] += xs * wv.y;
                acc[i][2] += xs * wv.z; acc[i][3] += xs * wv.w;
            }
        }
    }
#pragma unroll
    for (int i = 0; i < 4; i++) {
        long r = base + i;
        if (r < n) {
            *(float4*)(out + r * OUT_DIM + cg * 4) =
                make_float4(acc[i][0], acc[i][1], acc[i][2], acc[i][3]);
        }
    }
}

// ---------------- aggregation layer 1 (D=128, +bias, relu) ----------------
// one wave per node; lane handles 2 floats (float2 = 8B/lane, 512B/wave gather)

__global__ __launch_bounds__(256) void agg1_kernel(const float* __restrict__ h,
        const float* __restrict__ dinv, const int* __restrict__ offsets,
        const int* __restrict__ csc_row, const float* __restrict__ csc_norm,
        const float* __restrict__ b, float* __restrict__ out, int n) {
    int lane = threadIdx.x & 63;
    int node = blockIdx.x * 4 + (threadIdx.x >> 6);
    if (node >= n) return;
    float di = dinv[node];
    float self = di * di;
    float2 v = ((const float2*)(h + (long)node * HID_DIM))[lane];
    float ax = self * v.x, ay = self * v.y;
    float bx = 0.0f, by = 0.0f;
    int s = offsets[node], e = offsets[node + 1];
    int p = s;
    for (; p + 1 < e; p += 2) {           // 2-wide unroll: two gathers in flight
        int r0 = csc_row[p], r1 = csc_row[p + 1];
        float n0 = csc_norm[p], n1 = csc_norm[p + 1];
        float2 v0 = ((const float2*)(h + (long)r0 * HID_DIM))[lane];
        float2 v1 = ((const float2*)(h + (long)r1 * HID_DIM))[lane];
        ax += n0 * v0.x; ay += n0 * v0.y;
        bx += n1 * v1.x; by += n1 * v1.y;
    }
    if (p < e) {
        int r0 = csc_row[p];
        float n0 = csc_norm[p];
        float2 v0 = ((const float2*)(h + (long)r0 * HID_DIM))[lane];
        ax += n0 * v0.x; ay += n0 * v0.y;
    }
    ax += bx + b[lane * 2];
    ay += by + b[lane * 2 + 1];
    ax = fmaxf(ax, 0.0f);
    ay = fmaxf(ay, 0.0f);
    ((float2*)(out + (long)node * HID_DIM))[lane] = make_float2(ax, ay);
}

// ---------------- aggregation layer 2 (D=64, +bias, no relu) ----------------

__global__ __launch_bounds__(256) void agg2_kernel(const float* __restrict__ h,
        const float* __restrict__ dinv, const int* __restrict__ offsets,
        const int* __restrict__ csc_row, const float* __restrict__ csc_norm,
        const float* __restrict__ b, float* __restrict__ out, int n) {
    int lane = threadIdx.x & 63;
    int node = blockIdx.x * 4 + (threadIdx.x >> 6);
    if (node >= n) return;
    float di = dinv[node];
    float a0 = di * di * h[(long)node * OUT_DIM + lane];
    float a1 = 0.0f;
    int s = offsets[node], e = offsets[node + 1];
    int p = s;
    for (; p + 1 < e; p += 2) {
        int r0 = csc_row[p], r1 = csc_row[p + 1];
        float n0 = csc_norm[p], n1 = csc_norm[p + 1];
        a0 += n0 * h[(long)r0 * OUT_DIM + lane];
        a1 += n1 * h[(long)r1 * OUT_DIM + lane];
    }
    if (p < e) a0 += csc_norm[p] * h[(long)csc_row[p] * OUT_DIM + lane];
    out[(long)node * OUT_DIM + lane] = a0 + a1 + b[lane];
}

// ---------------- launch ----------------

extern "C" void kernel_launch(void* const* d_in, const int* in_sizes, int n_in,
                              void* d_out, int out_size, void* d_ws, size_t ws_size,
                              hipStream_t stream) {
    const float* x  = (const float*)d_in[0];
    const int*   ei = (const int*)d_in[1];
    const float* w  = (const float*)d_in[2];
    const float* W1 = (const float*)d_in[3];
    const float* b1 = (const float*)d_in[4];
    const float* W2 = (const float*)d_in[5];
    const float* b2 = (const float*)d_in[6];
    float* out = (float*)d_out;

    int N = in_sizes[0] / IN_DIM;       // 100000
    int E = in_sizes[2];                // 1600000
    const int* row = ei;
    const int* col = ei + E;

    // workspace carve (256B aligned regions)
    char* base = (char*)d_ws;
    size_t off = 0;
    auto alloc = [&](size_t bytes) -> void* {
        void* p = base + off;
        off += (bytes + 255) & ~(size_t)255;
        return p;
    };
    float* deg      = (float*)alloc((size_t)N * 4);          // becomes dinv in place
    int*   cnt      = (int*)  alloc((size_t)N * 4);
    int*   offsets  = (int*)  alloc((size_t)(N + 1) * 4);
    int*   cursors  = (int*)  alloc((size_t)N * 4);
    int*   csc_row  = (int*)  alloc((size_t)E * 4);
    float* csc_norm = (float*)alloc((size_t)E * 4);
    float* h        = (float*)alloc((size_t)N * HID_DIM * 4); // also reused as h2
    float* hagg     = (float*)alloc((size_t)N * HID_DIM * 4);

    int gN = (N + 255) / 256;
    int gE = (E + 255) / 256;
    int gGemm = (N + 63) / 64;
    int gAgg = (N + 3) / 4;

    init_kernel<<<gN, 256, 0, stream>>>(deg, cnt, N);
    deg_cnt_kernel<<<gE, 256, 0, stream>>>(col, w, deg, cnt, E);
    dinv_kernel<<<gN, 256, 0, stream>>>(deg, N);
    scan_kernel<<<1, 1024, 0, stream>>>(cnt, offsets, cursors, N);
    fill_csc_kernel<<<gE, 256, 0, stream>>>(row, col, w, deg, cursors,
                                            csc_row, csc_norm, E);
    gemm1_kernel<<<gGemm, 256, 0, stream>>>(x, W1, h, N);
    agg1_kernel<<<gAgg, 256, 0, stream>>>(h, deg, offsets, csc_row, csc_norm,
                                          b1, hagg, N);
    gemm2_kernel<<<gGemm, 256, 0, stream>>>(hagg, W2, h, N);   // h reused as h2
    agg2_kernel<<<gAgg, 256, 0, stream>>>(h, deg, offsets, csc_row, csc_norm,
                                          b2, out, N);
}

// Round 2
// 804.378 us; speedup vs baseline: 1.2790x; 1.2790x over previous
//
#include <hip/hip_runtime.h>

#define IN_DIM 256
#define HID_DIM 128
#define OUT_DIM 64

// ---------------- preprocessing ----------------

__global__ __launch_bounds__(256) void init_kernel(float* deg, int* cnt, int n) {
    int i = blockIdx.x * 256 + threadIdx.x;
    if (i < n) { deg[i] = 1.0f; cnt[i] = 0; }   // self-loop weight 1 pre-seeded
}

__global__ __launch_bounds__(256) void deg_cnt_kernel(const int* __restrict__ col,
        const float* __restrict__ w, float* deg, int* cnt, int e) {
    int i = blockIdx.x * 256 + threadIdx.x;
    if (i < e) {
        int c = col[i];
        atomicAdd(&deg[c], w[i]);
        atomicAdd(&cnt[c], 1);
    }
}

__global__ __launch_bounds__(256) void dinv_kernel(float* deg, int n) {
    int i = blockIdx.x * 256 + threadIdx.x;
    if (i < n) {
        float d = deg[i];
        deg[i] = d > 0.0f ? rsqrtf(d) : 0.0f;
    }
}

// ---- hierarchical exclusive scan: 1024 elems/block, 3 phases ----
// phase 1: per-block sums

__global__ __launch_bounds__(256) void scan1_kernel(const int* __restrict__ cnt,
        int* __restrict__ bsum, int n) {
    int t = threadIdx.x;
    int base = blockIdx.x * 1024 + t * 4;
    int s = 0;
    if (base + 3 < n) {
        int4 v = *(const int4*)(cnt + base);
        s = v.x + v.y + v.z + v.w;
    } else {
        for (int i = 0; i < 4; i++) if (base + i < n) s += cnt[base + i];
    }
    __shared__ int sm[256];
    sm[t] = s;
    __syncthreads();
    for (int d = 1; d < 256; d <<= 1) {
        int v = (t >= d) ? sm[t - d] : 0;
        __syncthreads();
        sm[t] += v;
        __syncthreads();
    }
    if (t == 255) bsum[blockIdx.x] = sm[255];
}

// phase 2: single block scans the (<=1024) block sums -> exclusive prefixes + total

__global__ __launch_bounds__(1024) void scan2_kernel(int* bsum, int* total_out, int nb) {
    __shared__ int sm[1024];
    int t = threadIdx.x;
    int v = (t < nb) ? bsum[t] : 0;
    sm[t] = v;
    __syncthreads();
    for (int d = 1; d < 1024; d <<= 1) {
        int u = (t >= d) ? sm[t - d] : 0;
        __syncthreads();
        sm[t] += u;
        __syncthreads();
    }
    int ex = (t == 0) ? 0 : sm[t - 1];
    if (t < nb) bsum[t] = ex;
    if (t == nb - 1) *total_out = sm[t];
}

// phase 3: rebuild in-block exclusive scan, add block prefix, write offsets+cursors

__global__ __launch_bounds__(256) void scan3_kernel(const int* __restrict__ cnt,
        const int* __restrict__ bsum, int* __restrict__ offsets,
        int* __restrict__ cursors, int n) {
    int t = threadIdx.x;
    int base = blockIdx.x * 1024 + t * 4;
    int a[4] = {0, 0, 0, 0};
    if (base + 3 < n) {
        int4 v = *(const int4*)(cnt + base);
        a[0] = v.x; a[1] = v.y; a[2] = v.z; a[3] = v.w;
    } else {
        for (int i = 0; i < 4; i++) if (base + i < n) a[i] = cnt[base + i];
    }
    int s = a[0] + a[1] + a[2] + a[3];
    __shared__ int sm[256];
    sm[t] = s;
    __syncthreads();
    for (int d = 1; d < 256; d <<= 1) {
        int u = (t >= d) ? sm[t - d] : 0;
        __syncthreads();
        sm[t] += u;
        __syncthreads();
    }
    int pre = bsum[blockIdx.x] + ((t == 0) ? 0 : sm[t - 1]);
    int o0 = pre, o1 = o0 + a[0], o2 = o1 + a[1], o3 = o2 + a[2];
    if (base + 3 < n) {
        *(int4*)(offsets + base) = make_int4(o0, o1, o2, o3);
        *(int4*)(cursors + base) = make_int4(o0, o1, o2, o3);
    } else {
        int o[4] = {o0, o1, o2, o3};
        for (int i = 0; i < 4; i++) if (base + i < n) {
            offsets[base + i] = o[i];
            cursors[base + i] = o[i];
        }
    }
}

__global__ __launch_bounds__(256) void fill_csc_kernel(const int* __restrict__ row,
        const int* __restrict__ col, const float* __restrict__ w,
        const float* __restrict__ dinv, int* cursors,
        int* csc_row, float* csc_norm, int e) {
    int i = blockIdx.x * 256 + threadIdx.x;
    if (i < e) {
        int r = row[i], c = col[i];
        float nrm = dinv[r] * w[i] * dinv[c];
        int p = atomicAdd(&cursors[c], 1);
        csc_row[p] = r;
        csc_norm[p] = nrm;
    }
}

// ---------------- GEMM 1: [N,256] @ [256,128] ----------------

__global__ __launch_bounds__(256) void gemm1_kernel(const float* __restrict__ x,
        const float* __restrict__ W, float* __restrict__ h, int n) {
    __shared__ float4 sW[4096];                       // 64 KB: 128 k-rows x 128 cols
    const float4* W4 = (const float4*)W;
    int t = threadIdx.x;
    int cg = t & 15;
    int ng = t >> 4;
    long base = (long)blockIdx.x * 64 + ng * 4;

    float acc[4][8];
#pragma unroll
    for (int i = 0; i < 4; i++)
#pragma unroll
        for (int j = 0; j < 8; j++) acc[i][j] = 0.0f;

    for (int half = 0; half < 2; half++) {
        __syncthreads();
        for (int i = t; i < 4096; i += 256) sW[i] = W4[half * 4096 + i];
        __syncthreads();
        int k0 = half * 128;
        for (int k = 0; k < 128; k += 4) {
            float4 xv[4];
#pragma unroll
            for (int i = 0; i < 4; i++) {
                long r = base + i; if (r > n - 1) r = n - 1;
                xv[i] = *(const float4*)(x + r * IN_DIM + k0 + k);
            }
#pragma unroll
            for (int kk = 0; kk < 4; kk++) {
                float4 w0 = sW[(k + kk) * 32 + cg * 2];
                float4 w1 = sW[(k + kk) * 32 + cg * 2 + 1];
#pragma unroll
                for (int i = 0; i < 4; i++) {
                    float xs = (kk == 0) ? xv[i].x : (kk == 1) ? xv[i].y
                             : (kk == 2) ? xv[i].z : xv[i].w;
                    acc[i][0] += xs * w0.x; acc[i][1] += xs * w0.y;
                    acc[i][2] += xs * w0.z; acc[i][3] += xs * w0.w;
                    acc[i][4] += xs * w1.x; acc[i][5] += xs * w1.y;
                    acc[i][6] += xs * w1.z; acc[i][7] += xs * w1.w;
                }
            }
        }
    }
#pragma unroll
    for (int i = 0; i < 4; i++) {
        long r = base + i;
        if (r < n) {
            float4* dst = (float4*)(h + r * HID_DIM + cg * 8);
            dst[0] = make_float4(acc[i][0], acc[i][1], acc[i][2], acc[i][3]);
            dst[1] = make_float4(acc[i][4], acc[i][5], acc[i][6], acc[i][7]);
        }
    }
}

// ---------------- GEMM 2: [N,128] @ [128,64] ----------------

__global__ __launch_bounds__(256) void gemm2_kernel(const float* __restrict__ a,
        const float* __restrict__ W, float* __restrict__ out, int n) {
    __shared__ float4 sW[2048];                       // 32 KB: 128 x 64
    const float4* W4 = (const float4*)W;
    int t = threadIdx.x;
    int cg = t & 15;
    int ng = t >> 4;
    long base = (long)blockIdx.x * 64 + ng * 4;
    for (int i = t; i < 2048; i += 256) sW[i] = W4[i];
    __syncthreads();

    float acc[4][4];
#pragma unroll
    for (int i = 0; i < 4; i++)
#pragma unroll
        for (int j = 0; j < 4; j++) acc[i][j] = 0.0f;

    for (int k = 0; k < HID_DIM; k += 4) {
        float4 xv[4];
#pragma unroll
        for (int i = 0; i < 4; i++) {
            long r = base + i; if (r > n - 1) r = n - 1;
            xv[i] = *(const float4*)(a + r * HID_DIM + k);
        }
#pragma unroll
        for (int kk = 0; kk < 4; kk++) {
            float4 wv = sW[(k + kk) * 16 + cg];
#pragma unroll
            for (int i = 0; i < 4; i++) {
                float xs = (kk == 0) ? xv[i].x : (kk == 1) ? xv[i].y
                         : (kk == 2) ? xv[i].z : xv[i].w;
                acc[i][0] += xs * wv.x; acc[i][1] += xs * wv.y;
                acc[i][2] += xs * wv.z; acc[i][3] += xs * wv.w;
            }
        }
    }
#pragma unroll
    for (int i = 0; i < 4; i++) {
        long r = base + i;
        if (r < n) {
            *(float4*)(out + r * OUT_DIM + cg * 4) =
                make_float4(acc[i][0], acc[i][1], acc[i][2], acc[i][3]);
        }
    }
}

// ---------------- aggregation layer 1 (D=128, +bias, relu) ----------------

__global__ __launch_bounds__(256) void agg1_kernel(const float* __restrict__ h,
        const float* __restrict__ dinv, const int* __restrict__ offsets,
        const int* __restrict__ csc_row, const float* __restrict__ csc_norm,
        const float* __restrict__ b, float* __restrict__ out, int n) {
    int lane = threadIdx.x & 63;
    int node = blockIdx.x * 4 + (threadIdx.x >> 6);
    if (node >= n) return;
    float di = dinv[node];
    float self = di * di;
    float2 v = ((const float2*)(h + (long)node * HID_DIM))[lane];
    float ax = self * v.x, ay = self * v.y;
    float bx = 0.0f, by = 0.0f;
    int s = offsets[node], e = offsets[node + 1];
    int p = s;
    for (; p + 1 < e; p += 2) {
        int r0 = csc_row[p], r1 = csc_row[p + 1];
        float n0 = csc_norm[p], n1 = csc_norm[p + 1];
        float2 v0 = ((const float2*)(h + (long)r0 * HID_DIM))[lane];
        float2 v1 = ((const float2*)(h + (long)r1 * HID_DIM))[lane];
        ax += n0 * v0.x; ay += n0 * v0.y;
        bx += n1 * v1.x; by += n1 * v1.y;
    }
    if (p < e) {
        int r0 = csc_row[p];
        float n0 = csc_norm[p];
        float2 v0 = ((const float2*)(h + (long)r0 * HID_DIM))[lane];
        ax += n0 * v0.x; ay += n0 * v0.y;
    }
    ax += bx + b[lane * 2];
    ay += by + b[lane * 2 + 1];
    ax = fmaxf(ax, 0.0f);
    ay = fmaxf(ay, 0.0f);
    ((float2*)(out + (long)node * HID_DIM))[lane] = make_float2(ax, ay);
}

// ---------------- aggregation layer 2 (D=64, +bias, no relu) ----------------

__global__ __launch_bounds__(256) void agg2_kernel(const float* __restrict__ h,
        const float* __restrict__ dinv, const int* __restrict__ offsets,
        const int* __restrict__ csc_row, const float* __restrict__ csc_norm,
        const float* __restrict__ b, float* __restrict__ out, int n) {
    int lane = threadIdx.x & 63;
    int node = blockIdx.x * 4 + (threadIdx.x >> 6);
    if (node >= n) return;
    float di = dinv[node];
    float a0 = di * di * h[(long)node * OUT_DIM + lane];
    float a1 = 0.0f;
    int s = offsets[node], e = offsets[node + 1];
    int p = s;
    for (; p + 1 < e; p += 2) {
        int r0 = csc_row[p], r1 = csc_row[p + 1];
        float n0 = csc_norm[p], n1 = csc_norm[p + 1];
        a0 += n0 * h[(long)r0 * OUT_DIM + lane];
        a1 += n1 * h[(long)r1 * OUT_DIM + lane];
    }
    if (p < e) a0 += csc_norm[p] * h[(long)csc_row[p] * OUT_DIM + lane];
    out[(long)node * OUT_DIM + lane] = a0 + a1 + b[lane];
}

// ---------------- launch ----------------

extern "C" void kernel_launch(void* const* d_in, const int* in_sizes, int n_in,
                              void* d_out, int out_size, void* d_ws, size_t ws_size,
                              hipStream_t stream) {
    const float* x  = (const float*)d_in[0];
    const int*   ei = (const int*)d_in[1];
    const float* w  = (const float*)d_in[2];
    const float* W1 = (const float*)d_in[3];
    const float* b1 = (const float*)d_in[4];
    const float* W2 = (const float*)d_in[5];
    const float* b2 = (const float*)d_in[6];
    float* out = (float*)d_out;

    int N = in_sizes[0] / IN_DIM;       // 100000
    int E = in_sizes[2];                // 1600000
    const int* row = ei;
    const int* col = ei + E;

    char* base = (char*)d_ws;
    size_t off = 0;
    auto alloc = [&](size_t bytes) -> void* {
        void* p = base + off;
        off += (bytes + 255) & ~(size_t)255;
        return p;
    };
    float* deg      = (float*)alloc((size_t)N * 4);
    int*   cnt      = (int*)  alloc((size_t)N * 4);
    int*   offsets  = (int*)  alloc((size_t)(N + 1) * 4);
    int*   cursors  = (int*)  alloc((size_t)N * 4);
    int*   bsum     = (int*)  alloc((size_t)1024 * 4);
    int*   csc_row  = (int*)  alloc((size_t)E * 4);
    float* csc_norm = (float*)alloc((size_t)E * 4);
    float* h        = (float*)alloc((size_t)N * HID_DIM * 4);
    float* hagg     = (float*)alloc((size_t)N * HID_DIM * 4);

    int gN = (N + 255) / 256;
    int gE = (E + 255) / 256;
    int gGemm = (N + 63) / 64;
    int gAgg = (N + 3) / 4;
    int nbScan = (N + 1023) / 1024;     // 98

    init_kernel<<<gN, 256, 0, stream>>>(deg, cnt, N);
    deg_cnt_kernel<<<gE, 256, 0, stream>>>(col, w, deg, cnt, E);
    dinv_kernel<<<gN, 256, 0, stream>>>(deg, N);
    scan1_kernel<<<nbScan, 256, 0, stream>>>(cnt, bsum, N);
    scan2_kernel<<<1, 1024, 0, stream>>>(bsum, offsets + N, nbScan);
    scan3_kernel<<<nbScan, 256, 0, stream>>>(cnt, bsum, offsets, cursors, N);
    fill_csc_kernel<<<gE, 256, 0, stream>>>(row, col, w, deg, cursors,
                                            csc_row, csc_norm, E);
    gemm1_kernel<<<gGemm, 256, 0, stream>>>(x, W1, h, N);
    agg1_kernel<<<gAgg, 256, 0, stream>>>(h, deg, offsets, csc_row, csc_norm,
                                          b1, hagg, N);
    gemm2_kernel<<<gGemm, 256, 0, stream>>>(hagg, W2, h, N);
    agg2_kernel<<<gAgg, 256, 0, stream>>>(h, deg, offsets, csc_row, csc_norm,
                                          b2, out, N);
}

// Round 3
// 713.515 us; speedup vs baseline: 1.4419x; 1.1273x over previous
//
#include <hip/hip_runtime.h>

#define IN_DIM 256
#define HID_DIM 128
#define OUT_DIM 64

typedef short s8v __attribute__((ext_vector_type(8)));
typedef float f32x4 __attribute__((ext_vector_type(4)));
typedef unsigned short ushort_t;

// ---------------- bf16 split helpers ----------------

__device__ __forceinline__ unsigned short bf16_rne(float f) {
    unsigned int u = __float_as_uint(f);
    u += 0x7FFFu + ((u >> 16) & 1u);
    return (unsigned short)(u >> 16);
}
__device__ __forceinline__ float bfbits_to_f(unsigned short h) {
    return __uint_as_float(((unsigned int)h) << 16);
}
__device__ __forceinline__ void cvt_split4(float4 f, uint2& hv, uint2& lv) {
    unsigned short h0 = bf16_rne(f.x), h1 = bf16_rne(f.y);
    unsigned short h2 = bf16_rne(f.z), h3 = bf16_rne(f.w);
    unsigned short l0 = bf16_rne(f.x - bfbits_to_f(h0));
    unsigned short l1 = bf16_rne(f.y - bfbits_to_f(h1));
    unsigned short l2 = bf16_rne(f.z - bfbits_to_f(h2));
    unsigned short l3 = bf16_rne(f.w - bfbits_to_f(h3));
    hv.x = (unsigned int)h0 | ((unsigned int)h1 << 16);
    hv.y = (unsigned int)h2 | ((unsigned int)h3 << 16);
    lv.x = (unsigned int)l0 | ((unsigned int)l1 << 16);
    lv.y = (unsigned int)l2 | ((unsigned int)l3 << 16);
}

// split W [K][NCOL] fp32 -> transposed bf16 hi/lo [NCOL][K]
__global__ __launch_bounds__(256) void wsplit_kernel(const float* __restrict__ W,
        unsigned short* __restrict__ wth, unsigned short* __restrict__ wtl,
        int K, int NCOL) {
    int idx = blockIdx.x * 256 + threadIdx.x;
    if (idx < K * NCOL) {
        int k = idx / NCOL, nn = idx % NCOL;
        float f = W[idx];
        unsigned short h = bf16_rne(f);
        unsigned short l = bf16_rne(f - bfbits_to_f(h));
        wth[nn * K + k] = h;
        wtl[nn * K + k] = l;
    }
}

// ---------------- preprocessing ----------------

__global__ __launch_bounds__(256) void init_kernel(float* deg, int* cnt, int n) {
    int i = blockIdx.x * 256 + threadIdx.x;
    if (i < n) { deg[i] = 1.0f; cnt[i] = 0; }
}

__global__ __launch_bounds__(256) void deg_cnt_kernel(const int* __restrict__ col,
        const float* __restrict__ w, float* deg, int* cnt, int e) {
    int i = blockIdx.x * 256 + threadIdx.x;
    if (i < e) {
        int c = col[i];
        atomicAdd(&deg[c], w[i]);
        atomicAdd(&cnt[c], 1);
    }
}

__global__ __launch_bounds__(256) void dinv_kernel(float* deg, int n) {
    int i = blockIdx.x * 256 + threadIdx.x;
    if (i < n) {
        float d = deg[i];
        deg[i] = d > 0.0f ? rsqrtf(d) : 0.0f;
    }
}

// ---- hierarchical exclusive scan ----

__global__ __launch_bounds__(256) void scan1_kernel(const int* __restrict__ cnt,
        int* __restrict__ bsum, int n) {
    int t = threadIdx.x;
    int base = blockIdx.x * 1024 + t * 4;
    int s = 0;
    if (base + 3 < n) {
        int4 v = *(const int4*)(cnt + base);
        s = v.x + v.y + v.z + v.w;
    } else {
        for (int i = 0; i < 4; i++) if (base + i < n) s += cnt[base + i];
    }
    __shared__ int sm[256];
    sm[t] = s;
    __syncthreads();
    for (int d = 1; d < 256; d <<= 1) {
        int v = (t >= d) ? sm[t - d] : 0;
        __syncthreads();
        sm[t] += v;
        __syncthreads();
    }
    if (t == 255) bsum[blockIdx.x] = sm[255];
}

__global__ __launch_bounds__(1024) void scan2_kernel(int* bsum, int* total_out, int nb) {
    __shared__ int sm[1024];
    int t = threadIdx.x;
    int v = (t < nb) ? bsum[t] : 0;
    sm[t] = v;
    __syncthreads();
    for (int d = 1; d < 1024; d <<= 1) {
        int u = (t >= d) ? sm[t - d] : 0;
        __syncthreads();
        sm[t] += u;
        __syncthreads();
    }
    int ex = (t == 0) ? 0 : sm[t - 1];
    if (t < nb) bsum[t] = ex;
    if (t == nb - 1) *total_out = sm[t];
}

__global__ __launch_bounds__(256) void scan3_kernel(const int* __restrict__ cnt,
        const int* __restrict__ bsum, int* __restrict__ offsets,
        int* __restrict__ cursors, int n) {
    int t = threadIdx.x;
    int base = blockIdx.x * 1024 + t * 4;
    int a[4] = {0, 0, 0, 0};
    if (base + 3 < n) {
        int4 v = *(const int4*)(cnt + base);
        a[0] = v.x; a[1] = v.y; a[2] = v.z; a[3] = v.w;
    } else {
        for (int i = 0; i < 4; i++) if (base + i < n) a[i] = cnt[base + i];
    }
    int s = a[0] + a[1] + a[2] + a[3];
    __shared__ int sm[256];
    sm[t] = s;
    __syncthreads();
    for (int d = 1; d < 256; d <<= 1) {
        int u = (t >= d) ? sm[t - d] : 0;
        __syncthreads();
        sm[t] += u;
        __syncthreads();
    }
    int pre = bsum[blockIdx.x] + ((t == 0) ? 0 : sm[t - 1]);
    int o0 = pre, o1 = o0 + a[0], o2 = o1 + a[1], o3 = o2 + a[2];
    if (base + 3 < n) {
        *(int4*)(offsets + base) = make_int4(o0, o1, o2, o3);
        *(int4*)(cursors + base) = make_int4(o0, o1, o2, o3);
    } else {
        int o[4] = {o0, o1, o2, o3};
        for (int i = 0; i < 4; i++) if (base + i < n) {
            offsets[base + i] = o[i];
            cursors[base + i] = o[i];
        }
    }
}

__global__ __launch_bounds__(256) void fill_csc_kernel(const int* __restrict__ row,
        const int* __restrict__ col, const float* __restrict__ w,
        const float* __restrict__ dinv, int* cursors,
        int* csc_row, float* csc_norm, int e) {
    int i = blockIdx.x * 256 + threadIdx.x;
    if (i < e) {
        int r = row[i], c = col[i];
        float nrm = dinv[r] * w[i] * dinv[c];
        int p = atomicAdd(&cursors[c], 1);
        csc_row[p] = r;
        csc_norm[p] = nrm;
    }
}

// ---------------- MFMA split-bf16 GEMM ----------------
// out[M,NCOL] = x[M,K] @ W[K,NCOL], W pre-split/transposed as bf16 hi/lo [NCOL][K].
// 3-pass split: x_hi*W_hi + x_lo*W_hi + x_hi*W_lo (fp32-grade accuracy).
// Block: 256 thr = 4 waves, 128 rows x NCOL out. Wave: 2 m-tiles x NT n-tiles.
// LDS rows padded to 40 bf16 (80B) -> 2-way bank aliasing (free, m136).

template<int K, int NCOL>
__global__ __launch_bounds__(256) void gemm_mfma_kernel(
        const float* __restrict__ x, const unsigned short* __restrict__ wth,
        const unsigned short* __restrict__ wtl, float* __restrict__ out, int n) {
    constexpr int NT = NCOL / 16;
    constexpr int NCH = K / 32;
    __shared__ unsigned short sAh[128 * 40];
    __shared__ unsigned short sAl[128 * 40];
    __shared__ unsigned short sBh[NCOL * 40];
    __shared__ unsigned short sBl[NCOL * 40];

    int t = threadIdx.x;
    int wave = t >> 6, lane = t & 63, quad = lane >> 4, r16 = lane & 15;
    long rowBase = (long)blockIdx.x * 128;

    f32x4 acc[2][NT];
#pragma unroll
    for (int mi = 0; mi < 2; mi++)
#pragma unroll
        for (int nt = 0; nt < NT; nt++) acc[mi][nt] = (f32x4)0.0f;

    int srow = t >> 1;                 // staging: row 0..127
    int skseg = (t & 1) * 16;          // k sub-segment 0 or 16
    long sgr = rowBase + srow; if (sgr > n - 1) sgr = n - 1;
    const float* xrow = x + sgr * K + skseg;

    for (int kc = 0; kc < NCH; kc++) {
        // ---- stage x chunk [128][32] fp32 -> bf16 hi/lo
        const float4* xs = (const float4*)(xrow + kc * 32);
        float4 f0 = xs[0], f1 = xs[1], f2 = xs[2], f3 = xs[3];
        uint2 h0, l0, h1, l1, h2, l2, h3, l3;
        cvt_split4(f0, h0, l0); cvt_split4(f1, h1, l1);
        cvt_split4(f2, h2, l2); cvt_split4(f3, h3, l3);
        *(uint4*)(sAh + srow * 40 + skseg)     = make_uint4(h0.x, h0.y, h1.x, h1.y);
        *(uint4*)(sAh + srow * 40 + skseg + 8) = make_uint4(h2.x, h2.y, h3.x, h3.y);
        *(uint4*)(sAl + srow * 40 + skseg)     = make_uint4(l0.x, l0.y, l1.x, l1.y);
        *(uint4*)(sAl + srow * 40 + skseg + 8) = make_uint4(l2.x, l2.y, l3.x, l3.y);
        // ---- stage W chunk [NCOL][32] bf16 hi/lo (pre-transposed)
        for (int c = t; c < NCOL * 4; c += 256) {
            int nn = c >> 2, ks = (c & 3) * 8;
            *(uint4*)(sBh + nn * 40 + ks) = *(const uint4*)(wth + nn * K + kc * 32 + ks);
            *(uint4*)(sBl + nn * 40 + ks) = *(const uint4*)(wtl + nn * K + kc * 32 + ks);
        }
        __syncthreads();
        // ---- fragments + MFMA
        const unsigned short* pa  = sAh + (wave * 32 + r16) * 40 + quad * 8;
        const unsigned short* pal = sAl + (wave * 32 + r16) * 40 + quad * 8;
        s8v ah0 = *(const s8v*)pa;
        s8v ah1 = *(const s8v*)(pa + 16 * 40);
        s8v al0 = *(const s8v*)pal;
        s8v al1 = *(const s8v*)(pal + 16 * 40);
#pragma unroll
        for (int nt = 0; nt < NT; nt++) {
            const unsigned short* pb  = sBh + (nt * 16 + r16) * 40 + quad * 8;
            const unsigned short* pbl = sBl + (nt * 16 + r16) * 40 + quad * 8;
            s8v bh = *(const s8v*)pb;
            s8v bl = *(const s8v*)pbl;
            acc[0][nt] = __builtin_amdgcn_mfma_f32_16x16x32_bf16(ah0, bh, acc[0][nt], 0, 0, 0);
            acc[0][nt] = __builtin_amdgcn_mfma_f32_16x16x32_bf16(al0, bh, acc[0][nt], 0, 0, 0);
            acc[0][nt] = __builtin_amdgcn_mfma_f32_16x16x32_bf16(ah0, bl, acc[0][nt], 0, 0, 0);
            acc[1][nt] = __builtin_amdgcn_mfma_f32_16x16x32_bf16(ah1, bh, acc[1][nt], 0, 0, 0);
            acc[1][nt] = __builtin_amdgcn_mfma_f32_16x16x32_bf16(al1, bh, acc[1][nt], 0, 0, 0);
            acc[1][nt] = __builtin_amdgcn_mfma_f32_16x16x32_bf16(ah1, bl, acc[1][nt], 0, 0, 0);
        }
        __syncthreads();
    }
    // ---- epilogue: C/D layout col=lane&15, row=quad*4+i
#pragma unroll
    for (int mi = 0; mi < 2; mi++) {
        long gr0 = rowBase + wave * 32 + mi * 16 + quad * 4;
#pragma unroll
        for (int nt = 0; nt < NT; nt++) {
            f32x4 d = acc[mi][nt];
#pragma unroll
            for (int i = 0; i < 4; i++) {
                long gr = gr0 + i;
                if (gr < n) out[gr * NCOL + nt * 16 + r16] = d[i];
            }
        }
    }
}

// ---------------- aggregation layer 1 (D=128, +bias, relu) ----------------

__global__ __launch_bounds__(256) void agg1_kernel(const float* __restrict__ h,
        const float* __restrict__ dinv, const int* __restrict__ offsets,
        const int* __restrict__ csc_row, const float* __restrict__ csc_norm,
        const float* __restrict__ b, float* __restrict__ out, int n) {
    int lane = threadIdx.x & 63;
    int node = blockIdx.x * 4 + (threadIdx.x >> 6);
    if (node >= n) return;
    float di = dinv[node];
    float self = di * di;
    float2 v = ((const float2*)(h + (long)node * HID_DIM))[lane];
    float ax = self * v.x, ay = self * v.y;
    float bx = 0.0f, by = 0.0f;
    int s = offsets[node], e = offsets[node + 1];
    int p = s;
    for (; p + 1 < e; p += 2) {
        int r0 = csc_row[p], r1 = csc_row[p + 1];
        float n0 = csc_norm[p], n1 = csc_norm[p + 1];
        float2 v0 = ((const float2*)(h + (long)r0 * HID_DIM))[lane];
        float2 v1 = ((const float2*)(h + (long)r1 * HID_DIM))[lane];
        ax += n0 * v0.x; ay += n0 * v0.y;
        bx += n1 * v1.x; by += n1 * v1.y;
    }
    if (p < e) {
        int r0 = csc_row[p];
        float n0 = csc_norm[p];
        float2 v0 = ((const float2*)(h + (long)r0 * HID_DIM))[lane];
        ax += n0 * v0.x; ay += n0 * v0.y;
    }
    ax += bx + b[lane * 2];
    ay += by + b[lane * 2 + 1];
    ax = fmaxf(ax, 0.0f);
    ay = fmaxf(ay, 0.0f);
    ((float2*)(out + (long)node * HID_DIM))[lane] = make_float2(ax, ay);
}

// ---------------- aggregation layer 2 (D=64, +bias) ----------------

__global__ __launch_bounds__(256) void agg2_kernel(const float* __restrict__ h,
        const float* __restrict__ dinv, const int* __restrict__ offsets,
        const int* __restrict__ csc_row, const float* __restrict__ csc_norm,
        const float* __restrict__ b, float* __restrict__ out, int n) {
    int lane = threadIdx.x & 63;
    int node = blockIdx.x * 4 + (threadIdx.x >> 6);
    if (node >= n) return;
    float di = dinv[node];
    float a0 = di * di * h[(long)node * OUT_DIM + lane];
    float a1 = 0.0f;
    int s = offsets[node], e = offsets[node + 1];
    int p = s;
    for (; p + 1 < e; p += 2) {
        int r0 = csc_row[p], r1 = csc_row[p + 1];
        float n0 = csc_norm[p], n1 = csc_norm[p + 1];
        a0 += n0 * h[(long)r0 * OUT_DIM + lane];
        a1 += n1 * h[(long)r1 * OUT_DIM + lane];
    }
    if (p < e) a0 += csc_norm[p] * h[(long)csc_row[p] * OUT_DIM + lane];
    out[(long)node * OUT_DIM + lane] = a0 + a1 + b[lane];
}

// ---------------- launch ----------------

extern "C" void kernel_launch(void* const* d_in, const int* in_sizes, int n_in,
                              void* d_out, int out_size, void* d_ws, size_t ws_size,
                              hipStream_t stream) {
    const float* x  = (const float*)d_in[0];
    const int*   ei = (const int*)d_in[1];
    const float* w  = (const float*)d_in[2];
    const float* W1 = (const float*)d_in[3];
    const float* b1 = (const float*)d_in[4];
    const float* W2 = (const float*)d_in[5];
    const float* b2 = (const float*)d_in[6];
    float* out = (float*)d_out;

    int N = in_sizes[0] / IN_DIM;       // 100000
    int E = in_sizes[2];                // 1600000
    const int* row = ei;
    const int* col = ei + E;

    char* base = (char*)d_ws;
    size_t off = 0;
    auto alloc = [&](size_t bytes) -> void* {
        void* p = base + off;
        off += (bytes + 255) & ~(size_t)255;
        return p;
    };
    float* deg      = (float*)alloc((size_t)N * 4);
    int*   cnt      = (int*)  alloc((size_t)N * 4);
    int*   offsets  = (int*)  alloc((size_t)(N + 1) * 4);
    int*   cursors  = (int*)  alloc((size_t)N * 4);
    int*   bsum     = (int*)  alloc((size_t)1024 * 4);
    int*   csc_row  = (int*)  alloc((size_t)E * 4);
    float* csc_norm = (float*)alloc((size_t)E * 4);
    float* h        = (float*)alloc((size_t)N * HID_DIM * 4);
    float* hagg     = (float*)alloc((size_t)N * HID_DIM * 4);
    unsigned short* wt1h = (unsigned short*)alloc((size_t)IN_DIM * HID_DIM * 2);
    unsigned short* wt1l = (unsigned short*)alloc((size_t)IN_DIM * HID_DIM * 2);
    unsigned short* wt2h = (unsigned short*)alloc((size_t)HID_DIM * OUT_DIM * 2);
    unsigned short* wt2l = (unsigned short*)alloc((size_t)HID_DIM * OUT_DIM * 2);

    int gN = (N + 255) / 256;
    int gE = (E + 255) / 256;
    int gGemm = (N + 127) / 128;
    int gAgg = (N + 3) / 4;
    int nbScan = (N + 1023) / 1024;

    wsplit_kernel<<<(IN_DIM * HID_DIM + 255) / 256, 256, 0, stream>>>(
        W1, wt1h, wt1l, IN_DIM, HID_DIM);
    wsplit_kernel<<<(HID_DIM * OUT_DIM + 255) / 256, 256, 0, stream>>>(
        W2, wt2h, wt2l, HID_DIM, OUT_DIM);
    init_kernel<<<gN, 256, 0, stream>>>(deg, cnt, N);
    deg_cnt_kernel<<<gE, 256, 0, stream>>>(col, w, deg, cnt, E);
    dinv_kernel<<<gN, 256, 0, stream>>>(deg, N);
    scan1_kernel<<<nbScan, 256, 0, stream>>>(cnt, bsum, N);
    scan2_kernel<<<1, 1024, 0, stream>>>(bsum, offsets + N, nbScan);
    scan3_kernel<<<nbScan, 256, 0, stream>>>(cnt, bsum, offsets, cursors, N);
    fill_csc_kernel<<<gE, 256, 0, stream>>>(row, col, w, deg, cursors,
                                            csc_row, csc_norm, E);
    gemm_mfma_kernel<IN_DIM, HID_DIM><<<gGemm, 256, 0, stream>>>(x, wt1h, wt1l, h, N);
    agg1_kernel<<<gAgg, 256, 0, stream>>>(h, deg, offsets, csc_row, csc_norm,
                                          b1, hagg, N);
    gemm_mfma_kernel<HID_DIM, OUT_DIM><<<gGemm, 256, 0, stream>>>(hagg, wt2h, wt2l, h, N);
    agg2_kernel<<<gAgg, 256, 0, stream>>>(h, deg, offsets, csc_row, csc_norm,
                                          b2, out, N);
}

// Round 4
// 661.431 us; speedup vs baseline: 1.5554x; 1.0787x over previous
//
#include <hip/hip_runtime.h>

#define IN_DIM 256
#define HID_DIM 128
#define OUT_DIM 64

typedef short s8v __attribute__((ext_vector_type(8)));
typedef float f32x4 __attribute__((ext_vector_type(4)));

// ---------------- bf16 split helpers ----------------

__device__ __forceinline__ unsigned short bf16_rne(float f) {
    unsigned int u = __float_as_uint(f);
    u += 0x7FFFu + ((u >> 16) & 1u);
    return (unsigned short)(u >> 16);
}
__device__ __forceinline__ float bfbits_to_f(unsigned short h) {
    return __uint_as_float(((unsigned int)h) << 16);
}
__device__ __forceinline__ void cvt_split4(float4 f, uint2& hv, uint2& lv) {
    unsigned short h0 = bf16_rne(f.x), h1 = bf16_rne(f.y);
    unsigned short h2 = bf16_rne(f.z), h3 = bf16_rne(f.w);
    unsigned short l0 = bf16_rne(f.x - bfbits_to_f(h0));
    unsigned short l1 = bf16_rne(f.y - bfbits_to_f(h1));
    unsigned short l2 = bf16_rne(f.z - bfbits_to_f(h2));
    unsigned short l3 = bf16_rne(f.w - bfbits_to_f(h3));
    hv.x = (unsigned int)h0 | ((unsigned int)h1 << 16);
    hv.y = (unsigned int)h2 | ((unsigned int)h3 << 16);
    lv.x = (unsigned int)l0 | ((unsigned int)l1 << 16);
    lv.y = (unsigned int)l2 | ((unsigned int)l3 << 16);
}

__global__ __launch_bounds__(256) void wsplit_kernel(const float* __restrict__ W,
        unsigned short* __restrict__ wth, unsigned short* __restrict__ wtl,
        int K, int NCOL) {
    int idx = blockIdx.x * 256 + threadIdx.x;
    if (idx < K * NCOL) {
        int k = idx / NCOL, nn = idx % NCOL;
        float f = W[idx];
        unsigned short h = bf16_rne(f);
        unsigned short l = bf16_rne(f - bfbits_to_f(h));
        wth[nn * K + k] = h;
        wtl[nn * K + k] = l;
    }
}

// ---------------- preprocessing ----------------

__global__ __launch_bounds__(256) void init_kernel(float* deg, int* cnt, int n) {
    int i = blockIdx.x * 256 + threadIdx.x;
    if (i < n) { deg[i] = 1.0f; cnt[i] = 0; }
}

__global__ __launch_bounds__(256) void deg_cnt_kernel(const int* __restrict__ col,
        const float* __restrict__ w, float* deg, int* cnt, int e) {
    int i = blockIdx.x * 256 + threadIdx.x;
    if (i < e) {
        int c = col[i];
        atomicAdd(&deg[c], w[i]);
        atomicAdd(&cnt[c], 1);
    }
}

__global__ __launch_bounds__(256) void dinv_kernel(float* deg, int n) {
    int i = blockIdx.x * 256 + threadIdx.x;
    if (i < n) {
        float d = deg[i];
        deg[i] = d > 0.0f ? rsqrtf(d) : 0.0f;
    }
}

// ---- hierarchical exclusive scan ----

__global__ __launch_bounds__(256) void scan1_kernel(const int* __restrict__ cnt,
        int* __restrict__ bsum, int n) {
    int t = threadIdx.x;
    int base = blockIdx.x * 1024 + t * 4;
    int s = 0;
    if (base + 3 < n) {
        int4 v = *(const int4*)(cnt + base);
        s = v.x + v.y + v.z + v.w;
    } else {
        for (int i = 0; i < 4; i++) if (base + i < n) s += cnt[base + i];
    }
    __shared__ int sm[256];
    sm[t] = s;
    __syncthreads();
    for (int d = 1; d < 256; d <<= 1) {
        int v = (t >= d) ? sm[t - d] : 0;
        __syncthreads();
        sm[t] += v;
        __syncthreads();
    }
    if (t == 255) bsum[blockIdx.x] = sm[255];
}

__global__ __launch_bounds__(1024) void scan2_kernel(int* bsum, int* total_out, int nb) {
    __shared__ int sm[1024];
    int t = threadIdx.x;
    int v = (t < nb) ? bsum[t] : 0;
    sm[t] = v;
    __syncthreads();
    for (int d = 1; d < 1024; d <<= 1) {
        int u = (t >= d) ? sm[t - d] : 0;
        __syncthreads();
        sm[t] += u;
        __syncthreads();
    }
    int ex = (t == 0) ? 0 : sm[t - 1];
    if (t < nb) bsum[t] = ex;
    if (t == nb - 1) *total_out = sm[t];
}

__global__ __launch_bounds__(256) void scan3_kernel(const int* __restrict__ cnt,
        const int* __restrict__ bsum, int* __restrict__ offsets,
        int* __restrict__ cursors, int n) {
    int t = threadIdx.x;
    int base = blockIdx.x * 1024 + t * 4;
    int a[4] = {0, 0, 0, 0};
    if (base + 3 < n) {
        int4 v = *(const int4*)(cnt + base);
        a[0] = v.x; a[1] = v.y; a[2] = v.z; a[3] = v.w;
    } else {
        for (int i = 0; i < 4; i++) if (base + i < n) a[i] = cnt[base + i];
    }
    int s = a[0] + a[1] + a[2] + a[3];
    __shared__ int sm[256];
    sm[t] = s;
    __syncthreads();
    for (int d = 1; d < 256; d <<= 1) {
        int u = (t >= d) ? sm[t - d] : 0;
        __syncthreads();
        sm[t] += u;
        __syncthreads();
    }
    int pre = bsum[blockIdx.x] + ((t == 0) ? 0 : sm[t - 1]);
    int o0 = pre, o1 = o0 + a[0], o2 = o1 + a[1], o3 = o2 + a[2];
    if (base + 3 < n) {
        *(int4*)(offsets + base) = make_int4(o0, o1, o2, o3);
        *(int4*)(cursors + base) = make_int4(o0, o1, o2, o3);
    } else {
        int o[4] = {o0, o1, o2, o3};
        for (int i = 0; i < 4; i++) if (base + i < n) {
            offsets[base + i] = o[i];
            cursors[base + i] = o[i];
        }
    }
}

__global__ __launch_bounds__(256) void fill_csc_kernel(const int* __restrict__ row,
        const int* __restrict__ col, const float* __restrict__ w,
        const float* __restrict__ dinv, int* cursors,
        int* csc_row, float* csc_norm, int e) {
    int i = blockIdx.x * 256 + threadIdx.x;
    if (i < e) {
        int r = row[i], c = col[i];
        float nrm = dinv[r] * w[i] * dinv[c];
        int p = atomicAdd(&cursors[c], 1);
        csc_row[p] = r;
        csc_norm[p] = nrm;
    }
}

// ---------------- MFMA split-bf16 GEMM ----------------

template<int K, int NCOL>
__global__ __launch_bounds__(256) void gemm_mfma_kernel(
        const float* __restrict__ x, const unsigned short* __restrict__ wth,
        const unsigned short* __restrict__ wtl, float* __restrict__ out, int n) {
    constexpr int NT = NCOL / 16;
    constexpr int NCH = K / 32;
    __shared__ unsigned short sAh[128 * 40];
    __shared__ unsigned short sAl[128 * 40];
    __shared__ unsigned short sBh[NCOL * 40];
    __shared__ unsigned short sBl[NCOL * 40];

    int t = threadIdx.x;
    int wave = t >> 6, lane = t & 63, quad = lane >> 4, r16 = lane & 15;
    long rowBase = (long)blockIdx.x * 128;

    f32x4 acc[2][NT];
#pragma unroll
    for (int mi = 0; mi < 2; mi++)
#pragma unroll
        for (int nt = 0; nt < NT; nt++) acc[mi][nt] = (f32x4)0.0f;

    int srow = t >> 1;
    int skseg = (t & 1) * 16;
    long sgr = rowBase + srow; if (sgr > n - 1) sgr = n - 1;
    const float* xrow = x + sgr * K + skseg;

    for (int kc = 0; kc < NCH; kc++) {
        const float4* xs = (const float4*)(xrow + kc * 32);
        float4 f0 = xs[0], f1 = xs[1], f2 = xs[2], f3 = xs[3];
        uint2 h0, l0, h1, l1, h2, l2, h3, l3;
        cvt_split4(f0, h0, l0); cvt_split4(f1, h1, l1);
        cvt_split4(f2, h2, l2); cvt_split4(f3, h3, l3);
        *(uint4*)(sAh + srow * 40 + skseg)     = make_uint4(h0.x, h0.y, h1.x, h1.y);
        *(uint4*)(sAh + srow * 40 + skseg + 8) = make_uint4(h2.x, h2.y, h3.x, h3.y);
        *(uint4*)(sAl + srow * 40 + skseg)     = make_uint4(l0.x, l0.y, l1.x, l1.y);
        *(uint4*)(sAl + srow * 40 + skseg + 8) = make_uint4(l2.x, l2.y, l3.x, l3.y);
        for (int c = t; c < NCOL * 4; c += 256) {
            int nn = c >> 2, ks = (c & 3) * 8;
            *(uint4*)(sBh + nn * 40 + ks) = *(const uint4*)(wth + nn * K + kc * 32 + ks);
            *(uint4*)(sBl + nn * 40 + ks) = *(const uint4*)(wtl + nn * K + kc * 32 + ks);
        }
        __syncthreads();
        const unsigned short* pa  = sAh + (wave * 32 + r16) * 40 + quad * 8;
        const unsigned short* pal = sAl + (wave * 32 + r16) * 40 + quad * 8;
        s8v ah0 = *(const s8v*)pa;
        s8v ah1 = *(const s8v*)(pa + 16 * 40);
        s8v al0 = *(const s8v*)pal;
        s8v al1 = *(const s8v*)(pal + 16 * 40);
#pragma unroll
        for (int nt = 0; nt < NT; nt++) {
            const unsigned short* pb  = sBh + (nt * 16 + r16) * 40 + quad * 8;
            const unsigned short* pbl = sBl + (nt * 16 + r16) * 40 + quad * 8;
            s8v bh = *(const s8v*)pb;
            s8v bl = *(const s8v*)pbl;
            acc[0][nt] = __builtin_amdgcn_mfma_f32_16x16x32_bf16(ah0, bh, acc[0][nt], 0, 0, 0);
            acc[0][nt] = __builtin_amdgcn_mfma_f32_16x16x32_bf16(al0, bh, acc[0][nt], 0, 0, 0);
            acc[0][nt] = __builtin_amdgcn_mfma_f32_16x16x32_bf16(ah0, bl, acc[0][nt], 0, 0, 0);
            acc[1][nt] = __builtin_amdgcn_mfma_f32_16x16x32_bf16(ah1, bh, acc[1][nt], 0, 0, 0);
            acc[1][nt] = __builtin_amdgcn_mfma_f32_16x16x32_bf16(al1, bh, acc[1][nt], 0, 0, 0);
            acc[1][nt] = __builtin_amdgcn_mfma_f32_16x16x32_bf16(ah1, bl, acc[1][nt], 0, 0, 0);
        }
        __syncthreads();
    }
#pragma unroll
    for (int mi = 0; mi < 2; mi++) {
        long gr0 = rowBase + wave * 32 + mi * 16 + quad * 4;
#pragma unroll
        for (int nt = 0; nt < NT; nt++) {
            f32x4 d = acc[mi][nt];
#pragma unroll
            for (int i = 0; i < 4; i++) {
                long gr = gr0 + i;
                if (gr < n) out[gr * NCOL + nt * 16 + r16] = d[i];
            }
        }
    }
}

// ---------------- aggregation layer 1 (D=128, +bias, relu) ----------------
// one wave per node; 32 lanes x float4 cover the row; 2 edge-streams per wave,
// each 2-unrolled -> 4 independent 512B gathers in flight.

__global__ __launch_bounds__(256) void agg1_kernel(const float* __restrict__ h,
        const float* __restrict__ dinv, const int* __restrict__ offsets,
        const int* __restrict__ csc_row, const float* __restrict__ csc_norm,
        const float* __restrict__ b, float* __restrict__ out, int n) {
    int t = threadIdx.x;
    int lane = t & 63;
    int strm = lane >> 5;            // 0..1
    int li = lane & 31;              // float4 index in row (32*4 = 128 dims)
    int node = blockIdx.x * 4 + (t >> 6);
    if (node >= n) return;

    float4 a0 = make_float4(0.f, 0.f, 0.f, 0.f);
    float4 a1 = make_float4(0.f, 0.f, 0.f, 0.f);
    int s = offsets[node], e = offsets[node + 1];

    if (strm == 0) {                 // self-loop term on stream 0
        float di = dinv[node];
        float sf = di * di;
        float4 v = ((const float4*)(h + (long)node * HID_DIM))[li];
        a0.x = sf * v.x; a0.y = sf * v.y; a0.z = sf * v.z; a0.w = sf * v.w;
    }

    int p = s + strm;
    for (; p + 2 < e; p += 4) {      // stream covers p, p+2, p+4, ... ; 2-unrolled
        int r0 = csc_row[p], r1 = csc_row[p + 2];
        float n0 = csc_norm[p], n1 = csc_norm[p + 2];
        float4 v0 = ((const float4*)(h + (long)r0 * HID_DIM))[li];
        float4 v1 = ((const float4*)(h + (long)r1 * HID_DIM))[li];
        a0.x += n0 * v0.x; a0.y += n0 * v0.y; a0.z += n0 * v0.z; a0.w += n0 * v0.w;
        a1.x += n1 * v1.x; a1.y += n1 * v1.y; a1.z += n1 * v1.z; a1.w += n1 * v1.w;
    }
    if (p < e) {
        int r0 = csc_row[p];
        float n0 = csc_norm[p];
        float4 v0 = ((const float4*)(h + (long)r0 * HID_DIM))[li];
        a0.x += n0 * v0.x; a0.y += n0 * v0.y; a0.z += n0 * v0.z; a0.w += n0 * v0.w;
    }
    a0.x += a1.x; a0.y += a1.y; a0.z += a1.z; a0.w += a1.w;
    // merge streams: lane li (strm0) += lane li+32 (strm1)
    a0.x += __shfl_down(a0.x, 32);
    a0.y += __shfl_down(a0.y, 32);
    a0.z += __shfl_down(a0.z, 32);
    a0.w += __shfl_down(a0.w, 32);
    if (strm == 0) {
        float4 bv = ((const float4*)b)[li];
        a0.x = fmaxf(a0.x + bv.x, 0.f);
        a0.y = fmaxf(a0.y + bv.y, 0.f);
        a0.z = fmaxf(a0.z + bv.z, 0.f);
        a0.w = fmaxf(a0.w + bv.w, 0.f);
        ((float4*)(out + (long)node * HID_DIM))[li] = a0;
    }
}

// ---------------- aggregation layer 2 (D=64, +bias) ----------------
// 16 lanes x float4 cover the row; 4 edge-streams per wave, 2-unrolled
// -> 8 independent gathers in flight.

__global__ __launch_bounds__(256) void agg2_kernel(const float* __restrict__ h,
        const float* __restrict__ dinv, const int* __restrict__ offsets,
        const int* __restrict__ csc_row, const float* __restrict__ csc_norm,
        const float* __restrict__ b, float* __restrict__ out, int n) {
    int t = threadIdx.x;
    int lane = t & 63;
    int strm = lane >> 4;            // 0..3
    int li = lane & 15;              // float4 index in row (16*4 = 64 dims)
    int node = blockIdx.x * 4 + (t >> 6);
    if (node >= n) return;

    float4 a0 = make_float4(0.f, 0.f, 0.f, 0.f);
    float4 a1 = make_float4(0.f, 0.f, 0.f, 0.f);
    int s = offsets[node], e = offsets[node + 1];

    if (strm == 0) {
        float di = dinv[node];
        float sf = di * di;
        float4 v = ((const float4*)(h + (long)node * OUT_DIM))[li];
        a0.x = sf * v.x; a0.y = sf * v.y; a0.z = sf * v.z; a0.w = sf * v.w;
    }

    int p = s + strm;
    for (; p + 4 < e; p += 8) {      // stream covers p, p+4, p+8, ...; 2-unrolled
        int r0 = csc_row[p], r1 = csc_row[p + 4];
        float n0 = csc_norm[p], n1 = csc_norm[p + 4];
        float4 v0 = ((const float4*)(h + (long)r0 * OUT_DIM))[li];
        float4 v1 = ((const float4*)(h + (long)r1 * OUT_DIM))[li];
        a0.x += n0 * v0.x; a0.y += n0 * v0.y; a0.z += n0 * v0.z; a0.w += n0 * v0.w;
        a1.x += n1 * v1.x; a1.y += n1 * v1.y; a1.z += n1 * v1.z; a1.w += n1 * v1.w;
    }
    if (p < e) {
        int r0 = csc_row[p];
        float n0 = csc_norm[p];
        float4 v0 = ((const float4*)(h + (long)r0 * OUT_DIM))[li];
        a0.x += n0 * v0.x; a0.y += n0 * v0.y; a0.z += n0 * v0.z; a0.w += n0 * v0.w;
    }
    a0.x += a1.x; a0.y += a1.y; a0.z += a1.z; a0.w += a1.w;
    // merge 4 streams
    a0.x += __shfl_down(a0.x, 32);
    a0.y += __shfl_down(a0.y, 32);
    a0.z += __shfl_down(a0.z, 32);
    a0.w += __shfl_down(a0.w, 32);
    a0.x += __shfl_down(a0.x, 16);
    a0.y += __shfl_down(a0.y, 16);
    a0.z += __shfl_down(a0.z, 16);
    a0.w += __shfl_down(a0.w, 16);
    if (strm == 0) {
        float4 bv = ((const float4*)b)[li];
        a0.x += bv.x; a0.y += bv.y; a0.z += bv.z; a0.w += bv.w;
        ((float4*)(out + (long)node * OUT_DIM))[li] = a0;
    }
}

// ---------------- launch ----------------

extern "C" void kernel_launch(void* const* d_in, const int* in_sizes, int n_in,
                              void* d_out, int out_size, void* d_ws, size_t ws_size,
                              hipStream_t stream) {
    const float* x  = (const float*)d_in[0];
    const int*   ei = (const int*)d_in[1];
    const float* w  = (const float*)d_in[2];
    const float* W1 = (const float*)d_in[3];
    const float* b1 = (const float*)d_in[4];
    const float* W2 = (const float*)d_in[5];
    const float* b2 = (const float*)d_in[6];
    float* out = (float*)d_out;

    int N = in_sizes[0] / IN_DIM;       // 100000
    int E = in_sizes[2];                // 1600000
    const int* row = ei;
    const int* col = ei + E;

    char* base = (char*)d_ws;
    size_t off = 0;
    auto alloc = [&](size_t bytes) -> void* {
        void* p = base + off;
        off += (bytes + 255) & ~(size_t)255;
        return p;
    };
    float* deg      = (float*)alloc((size_t)N * 4);
    int*   cnt      = (int*)  alloc((size_t)N * 4);
    int*   offsets  = (int*)  alloc((size_t)(N + 1) * 4);
    int*   cursors  = (int*)  alloc((size_t)N * 4);
    int*   bsum     = (int*)  alloc((size_t)1024 * 4);
    int*   csc_row  = (int*)  alloc((size_t)E * 4);
    float* csc_norm = (float*)alloc((size_t)E * 4);
    float* h        = (float*)alloc((size_t)N * HID_DIM * 4);
    float* hagg     = (float*)alloc((size_t)N * HID_DIM * 4);
    unsigned short* wt1h = (unsigned short*)alloc((size_t)IN_DIM * HID_DIM * 2);
    unsigned short* wt1l = (unsigned short*)alloc((size_t)IN_DIM * HID_DIM * 2);
    unsigned short* wt2h = (unsigned short*)alloc((size_t)HID_DIM * OUT_DIM * 2);
    unsigned short* wt2l = (unsigned short*)alloc((size_t)HID_DIM * OUT_DIM * 2);

    int gN = (N + 255) / 256;
    int gE = (E + 255) / 256;
    int gGemm = (N + 127) / 128;
    int gAgg = (N + 3) / 4;
    int nbScan = (N + 1023) / 1024;

    wsplit_kernel<<<(IN_DIM * HID_DIM + 255) / 256, 256, 0, stream>>>(
        W1, wt1h, wt1l, IN_DIM, HID_DIM);
    wsplit_kernel<<<(HID_DIM * OUT_DIM + 255) / 256, 256, 0, stream>>>(
        W2, wt2h, wt2l, HID_DIM, OUT_DIM);
    init_kernel<<<gN, 256, 0, stream>>>(deg, cnt, N);
    deg_cnt_kernel<<<gE, 256, 0, stream>>>(col, w, deg, cnt, E);
    dinv_kernel<<<gN, 256, 0, stream>>>(deg, N);
    scan1_kernel<<<nbScan, 256, 0, stream>>>(cnt, bsum, N);
    scan2_kernel<<<1, 1024, 0, stream>>>(bsum, offsets + N, nbScan);
    scan3_kernel<<<nbScan, 256, 0, stream>>>(cnt, bsum, offsets, cursors, N);
    fill_csc_kernel<<<gE, 256, 0, stream>>>(row, col, w, deg, cursors,
                                            csc_row, csc_norm, E);
    gemm_mfma_kernel<IN_DIM, HID_DIM><<<gGemm, 256, 0, stream>>>(x, wt1h, wt1l, h, N);
    agg1_kernel<<<gAgg, 256, 0, stream>>>(h, deg, offsets, csc_row, csc_norm,
                                          b1, hagg, N);
    gemm_mfma_kernel<HID_DIM, OUT_DIM><<<gGemm, 256, 0, stream>>>(hagg, wt2h, wt2l, h, N);
    agg2_kernel<<<gAgg, 256, 0, stream>>>(h, deg, offsets, csc_row, csc_norm,
                                          b2, out, N);
}

// Round 5
// 549.478 us; speedup vs baseline: 1.8723x; 1.2037x over previous
//
#include <hip/hip_runtime.h>

#define IN_DIM 256
#define HID_DIM 128
#define OUT_DIM 64

typedef short s8v __attribute__((ext_vector_type(8)));
typedef float f32x4 __attribute__((ext_vector_type(4)));

// ---------------- bf16 split helpers ----------------

__device__ __forceinline__ unsigned short bf16_rne(float f) {
    unsigned int u = __float_as_uint(f);
    u += 0x7FFFu + ((u >> 16) & 1u);
    return (unsigned short)(u >> 16);
}
__device__ __forceinline__ float bfbits_to_f(unsigned short h) {
    return __uint_as_float(((unsigned int)h) << 16);
}
__device__ __forceinline__ void cvt_split4(float4 f, uint2& hv, uint2& lv) {
    unsigned short h0 = bf16_rne(f.x), h1 = bf16_rne(f.y);
    unsigned short h2 = bf16_rne(f.z), h3 = bf16_rne(f.w);
    unsigned short l0 = bf16_rne(f.x - bfbits_to_f(h0));
    unsigned short l1 = bf16_rne(f.y - bfbits_to_f(h1));
    unsigned short l2 = bf16_rne(f.z - bfbits_to_f(h2));
    unsigned short l3 = bf16_rne(f.w - bfbits_to_f(h3));
    hv.x = (unsigned int)h0 | ((unsigned int)h1 << 16);
    hv.y = (unsigned int)h2 | ((unsigned int)h3 << 16);
    lv.x = (unsigned int)l0 | ((unsigned int)l1 << 16);
    lv.y = (unsigned int)l2 | ((unsigned int)l3 << 16);
}

__global__ __launch_bounds__(256) void wsplit_kernel(const float* __restrict__ W,
        unsigned short* __restrict__ wth, unsigned short* __restrict__ wtl,
        int K, int NCOL) {
    int idx = blockIdx.x * 256 + threadIdx.x;
    if (idx < K * NCOL) {
        int k = idx / NCOL, nn = idx % NCOL;
        float f = W[idx];
        unsigned short h = bf16_rne(f);
        unsigned short l = bf16_rne(f - bfbits_to_f(h));
        wth[nn * K + k] = h;
        wtl[nn * K + k] = l;
    }
}

// ---------------- preprocessing ----------------
// packed[i]: bits [63:40] = edge count, bits [39:0] = fixed-point (2^-24) sum of w.
// Init = 1.0 (self-loop weight), count 0.

#define FPSCALE 16777216.0f
#define FPMASK  ((1ULL << 40) - 1)

__global__ __launch_bounds__(256) void init_kernel(unsigned long long* packed, int n) {
    int i = blockIdx.x * 256 + threadIdx.x;
    if (i < n) packed[i] = (1ULL << 24);      // deg = 1.0, cnt = 0
}

__global__ __launch_bounds__(256) void deg_cnt_kernel(const int* __restrict__ col,
        const float* __restrict__ w, unsigned long long* packed, int e) {
    int i = blockIdx.x * 256 + threadIdx.x;
    if (i < e) {
        unsigned long long v = (1ULL << 40) |
            (unsigned long long)(w[i] * FPSCALE + 0.5f);
        atomicAdd(&packed[col[i]], v);
    }
}

__global__ __launch_bounds__(256) void dinv_kernel(const unsigned long long* __restrict__ packed,
        float* __restrict__ dinv, int* __restrict__ cnt, int n) {
    int i = blockIdx.x * 256 + threadIdx.x;
    if (i < n) {
        unsigned long long p = packed[i];
        float d = (float)(p & FPMASK) * (1.0f / FPSCALE);
        dinv[i] = d > 0.0f ? rsqrtf(d) : 0.0f;
        cnt[i] = (int)(p >> 40);
    }
}

// ---- hierarchical exclusive scan ----

__global__ __launch_bounds__(256) void scan1_kernel(const int* __restrict__ cnt,
        int* __restrict__ bsum, int n) {
    int t = threadIdx.x;
    int base = blockIdx.x * 1024 + t * 4;
    int s = 0;
    if (base + 3 < n) {
        int4 v = *(const int4*)(cnt + base);
        s = v.x + v.y + v.z + v.w;
    } else {
        for (int i = 0; i < 4; i++) if (base + i < n) s += cnt[base + i];
    }
    __shared__ int sm[256];
    sm[t] = s;
    __syncthreads();
    for (int d = 1; d < 256; d <<= 1) {
        int v = (t >= d) ? sm[t - d] : 0;
        __syncthreads();
        sm[t] += v;
        __syncthreads();
    }
    if (t == 255) bsum[blockIdx.x] = sm[255];
}

__global__ __launch_bounds__(1024) void scan2_kernel(int* bsum, int* total_out, int nb) {
    __shared__ int sm[1024];
    int t = threadIdx.x;
    int v = (t < nb) ? bsum[t] : 0;
    sm[t] = v;
    __syncthreads();
    for (int d = 1; d < 1024; d <<= 1) {
        int u = (t >= d) ? sm[t - d] : 0;
        __syncthreads();
        sm[t] += u;
        __syncthreads();
    }
    int ex = (t == 0) ? 0 : sm[t - 1];
    if (t < nb) bsum[t] = ex;
    if (t == nb - 1) *total_out = sm[t];
}

__global__ __launch_bounds__(256) void scan3_kernel(const int* __restrict__ cnt,
        const int* __restrict__ bsum, int* __restrict__ offsets,
        int* __restrict__ cursors, int n) {
    int t = threadIdx.x;
    int base = blockIdx.x * 1024 + t * 4;
    int a[4] = {0, 0, 0, 0};
    if (base + 3 < n) {
        int4 v = *(const int4*)(cnt + base);
        a[0] = v.x; a[1] = v.y; a[2] = v.z; a[3] = v.w;
    } else {
        for (int i = 0; i < 4; i++) if (base + i < n) a[i] = cnt[base + i];
    }
    int s = a[0] + a[1] + a[2] + a[3];
    __shared__ int sm[256];
    sm[t] = s;
    __syncthreads();
    for (int d = 1; d < 256; d <<= 1) {
        int u = (t >= d) ? sm[t - d] : 0;
        __syncthreads();
        sm[t] += u;
        __syncthreads();
    }
    int pre = bsum[blockIdx.x] + ((t == 0) ? 0 : sm[t - 1]);
    int o0 = pre, o1 = o0 + a[0], o2 = o1 + a[1], o3 = o2 + a[2];
    if (base + 3 < n) {
        *(int4*)(offsets + base) = make_int4(o0, o1, o2, o3);
        *(int4*)(cursors + base) = make_int4(o0, o1, o2, o3);
    } else {
        int o[4] = {o0, o1, o2, o3};
        for (int i = 0; i < 4; i++) if (base + i < n) {
            offsets[base + i] = o[i];
            cursors[base + i] = o[i];
        }
    }
}

// CSC entry: int2{ src_row, float_bits(norm) } — one 8B scattered store per edge.

__global__ __launch_bounds__(256) void fill_csc_kernel(const int* __restrict__ row,
        const int* __restrict__ col, const float* __restrict__ w,
        const float* __restrict__ dinv, int* cursors,
        int2* __restrict__ csc, int e) {
    int i = blockIdx.x * 256 + threadIdx.x;
    if (i < e) {
        int r = row[i], c = col[i];
        float nrm = dinv[r] * w[i] * dinv[c];
        int p = atomicAdd(&cursors[c], 1);
        csc[p] = make_int2(r, __float_as_int(nrm));
    }
}

// ---------------- MFMA split-bf16 GEMM ----------------

template<int K, int NCOL>
__global__ __launch_bounds__(256) void gemm_mfma_kernel(
        const float* __restrict__ x, const unsigned short* __restrict__ wth,
        const unsigned short* __restrict__ wtl, float* __restrict__ out, int n) {
    constexpr int NT = NCOL / 16;
    constexpr int NCH = K / 32;
    __shared__ unsigned short sAh[128 * 40];
    __shared__ unsigned short sAl[128 * 40];
    __shared__ unsigned short sBh[NCOL * 40];
    __shared__ unsigned short sBl[NCOL * 40];

    int t = threadIdx.x;
    int wave = t >> 6, lane = t & 63, quad = lane >> 4, r16 = lane & 15;
    long rowBase = (long)blockIdx.x * 128;

    f32x4 acc[2][NT];
#pragma unroll
    for (int mi = 0; mi < 2; mi++)
#pragma unroll
        for (int nt = 0; nt < NT; nt++) acc[mi][nt] = (f32x4)0.0f;

    int srow = t >> 1;
    int skseg = (t & 1) * 16;
    long sgr = rowBase + srow; if (sgr > n - 1) sgr = n - 1;
    const float* xrow = x + sgr * K + skseg;

    for (int kc = 0; kc < NCH; kc++) {
        const float4* xs = (const float4*)(xrow + kc * 32);
        float4 f0 = xs[0], f1 = xs[1], f2 = xs[2], f3 = xs[3];
        uint2 h0, l0, h1, l1, h2, l2, h3, l3;
        cvt_split4(f0, h0, l0); cvt_split4(f1, h1, l1);
        cvt_split4(f2, h2, l2); cvt_split4(f3, h3, l3);
        *(uint4*)(sAh + srow * 40 + skseg)     = make_uint4(h0.x, h0.y, h1.x, h1.y);
        *(uint4*)(sAh + srow * 40 + skseg + 8) = make_uint4(h2.x, h2.y, h3.x, h3.y);
        *(uint4*)(sAl + srow * 40 + skseg)     = make_uint4(l0.x, l0.y, l1.x, l1.y);
        *(uint4*)(sAl + srow * 40 + skseg + 8) = make_uint4(l2.x, l2.y, l3.x, l3.y);
        for (int c = t; c < NCOL * 4; c += 256) {
            int nn = c >> 2, ks = (c & 3) * 8;
            *(uint4*)(sBh + nn * 40 + ks) = *(const uint4*)(wth + nn * K + kc * 32 + ks);
            *(uint4*)(sBl + nn * 40 + ks) = *(const uint4*)(wtl + nn * K + kc * 32 + ks);
        }
        __syncthreads();
        const unsigned short* pa  = sAh + (wave * 32 + r16) * 40 + quad * 8;
        const unsigned short* pal = sAl + (wave * 32 + r16) * 40 + quad * 8;
        s8v ah0 = *(const s8v*)pa;
        s8v ah1 = *(const s8v*)(pa + 16 * 40);
        s8v al0 = *(const s8v*)pal;
        s8v al1 = *(const s8v*)(pal + 16 * 40);
#pragma unroll
        for (int nt = 0; nt < NT; nt++) {
            const unsigned short* pb  = sBh + (nt * 16 + r16) * 40 + quad * 8;
            const unsigned short* pbl = sBl + (nt * 16 + r16) * 40 + quad * 8;
            s8v bh = *(const s8v*)pb;
            s8v bl = *(const s8v*)pbl;
            acc[0][nt] = __builtin_amdgcn_mfma_f32_16x16x32_bf16(ah0, bh, acc[0][nt], 0, 0, 0);
            acc[0][nt] = __builtin_amdgcn_mfma_f32_16x16x32_bf16(al0, bh, acc[0][nt], 0, 0, 0);
            acc[0][nt] = __builtin_amdgcn_mfma_f32_16x16x32_bf16(ah0, bl, acc[0][nt], 0, 0, 0);
            acc[1][nt] = __builtin_amdgcn_mfma_f32_16x16x32_bf16(ah1, bh, acc[1][nt], 0, 0, 0);
            acc[1][nt] = __builtin_amdgcn_mfma_f32_16x16x32_bf16(al1, bh, acc[1][nt], 0, 0, 0);
            acc[1][nt] = __builtin_amdgcn_mfma_f32_16x16x32_bf16(ah1, bl, acc[1][nt], 0, 0, 0);
        }
        __syncthreads();
    }
#pragma unroll
    for (int mi = 0; mi < 2; mi++) {
        long gr0 = rowBase + wave * 32 + mi * 16 + quad * 4;
#pragma unroll
        for (int nt = 0; nt < NT; nt++) {
            f32x4 d = acc[mi][nt];
#pragma unroll
            for (int i = 0; i < 4; i++) {
                long gr = gr0 + i;
                if (gr < n) out[gr * NCOL + nt * 16 + r16] = d[i];
            }
        }
    }
}

// ---------------- aggregation layer 1 (D=128, +bias, relu) ----------------

__global__ __launch_bounds__(256) void agg1_kernel(const float* __restrict__ h,
        const float* __restrict__ dinv, const int* __restrict__ offsets,
        const int2* __restrict__ csc, const float* __restrict__ b,
        float* __restrict__ out, int n) {
    int t = threadIdx.x;
    int lane = t & 63;
    int strm = lane >> 5;            // 0..1
    int li = lane & 31;              // float4 index in row (32*4 = 128 dims)
    int node = blockIdx.x * 4 + (t >> 6);
    if (node >= n) return;

    float4 a0 = make_float4(0.f, 0.f, 0.f, 0.f);
    float4 a1 = make_float4(0.f, 0.f, 0.f, 0.f);
    int s = offsets[node], e = offsets[node + 1];

    if (strm == 0) {
        float di = dinv[node];
        float sf = di * di;
        float4 v = ((const float4*)(h + (long)node * HID_DIM))[li];
        a0.x = sf * v.x; a0.y = sf * v.y; a0.z = sf * v.z; a0.w = sf * v.w;
    }

    int p = s + strm;
    for (; p + 2 < e; p += 4) {
        int2 e0 = csc[p], e1 = csc[p + 2];
        float n0 = __int_as_float(e0.y), n1 = __int_as_float(e1.y);
        float4 v0 = ((const float4*)(h + (long)e0.x * HID_DIM))[li];
        float4 v1 = ((const float4*)(h + (long)e1.x * HID_DIM))[li];
        a0.x += n0 * v0.x; a0.y += n0 * v0.y; a0.z += n0 * v0.z; a0.w += n0 * v0.w;
        a1.x += n1 * v1.x; a1.y += n1 * v1.y; a1.z += n1 * v1.z; a1.w += n1 * v1.w;
    }
    if (p < e) {
        int2 e0 = csc[p];
        float n0 = __int_as_float(e0.y);
        float4 v0 = ((const float4*)(h + (long)e0.x * HID_DIM))[li];
        a0.x += n0 * v0.x; a0.y += n0 * v0.y; a0.z += n0 * v0.z; a0.w += n0 * v0.w;
    }
    a0.x += a1.x; a0.y += a1.y; a0.z += a1.z; a0.w += a1.w;
    a0.x += __shfl_down(a0.x, 32);
    a0.y += __shfl_down(a0.y, 32);
    a0.z += __shfl_down(a0.z, 32);
    a0.w += __shfl_down(a0.w, 32);
    if (strm == 0) {
        float4 bv = ((const float4*)b)[li];
        a0.x = fmaxf(a0.x + bv.x, 0.f);
        a0.y = fmaxf(a0.y + bv.y, 0.f);
        a0.z = fmaxf(a0.z + bv.z, 0.f);
        a0.w = fmaxf(a0.w + bv.w, 0.f);
        ((float4*)(out + (long)node * HID_DIM))[li] = a0;
    }
}

// ---------------- aggregation layer 2 (D=64, +bias) ----------------

__global__ __launch_bounds__(256) void agg2_kernel(const float* __restrict__ h,
        const float* __restrict__ dinv, const int* __restrict__ offsets,
        const int2* __restrict__ csc, const float* __restrict__ b,
        float* __restrict__ out, int n) {
    int t = threadIdx.x;
    int lane = t & 63;
    int strm = lane >> 4;            // 0..3
    int li = lane & 15;              // float4 index in row (16*4 = 64 dims)
    int node = blockIdx.x * 4 + (t >> 6);
    if (node >= n) return;

    float4 a0 = make_float4(0.f, 0.f, 0.f, 0.f);
    float4 a1 = make_float4(0.f, 0.f, 0.f, 0.f);
    int s = offsets[node], e = offsets[node + 1];

    if (strm == 0) {
        float di = dinv[node];
        float sf = di * di;
        float4 v = ((const float4*)(h + (long)node * OUT_DIM))[li];
        a0.x = sf * v.x; a0.y = sf * v.y; a0.z = sf * v.z; a0.w = sf * v.w;
    }

    int p = s + strm;
    for (; p + 4 < e; p += 8) {
        int2 e0 = csc[p], e1 = csc[p + 4];
        float n0 = __int_as_float(e0.y), n1 = __int_as_float(e1.y);
        float4 v0 = ((const float4*)(h + (long)e0.x * OUT_DIM))[li];
        float4 v1 = ((const float4*)(h + (long)e1.x * OUT_DIM))[li];
        a0.x += n0 * v0.x; a0.y += n0 * v0.y; a0.z += n0 * v0.z; a0.w += n0 * v0.w;
        a1.x += n1 * v1.x; a1.y += n1 * v1.y; a1.z += n1 * v1.z; a1.w += n1 * v1.w;
    }
    if (p < e) {
        int2 e0 = csc[p];
        float n0 = __int_as_float(e0.y);
        float4 v0 = ((const float4*)(h + (long)e0.x * OUT_DIM))[li];
        a0.x += n0 * v0.x; a0.y += n0 * v0.y; a0.z += n0 * v0.z; a0.w += n0 * v0.w;
    }
    a0.x += a1.x; a0.y += a1.y; a0.z += a1.z; a0.w += a1.w;
    a0.x += __shfl_down(a0.x, 32);
    a0.y += __shfl_down(a0.y, 32);
    a0.z += __shfl_down(a0.z, 32);
    a0.w += __shfl_down(a0.w, 32);
    a0.x += __shfl_down(a0.x, 16);
    a0.y += __shfl_down(a0.y, 16);
    a0.z += __shfl_down(a0.z, 16);
    a0.w += __shfl_down(a0.w, 16);
    if (strm == 0) {
        float4 bv = ((const float4*)b)[li];
        a0.x += bv.x; a0.y += bv.y; a0.z += bv.z; a0.w += bv.w;
        ((float4*)(out + (long)node * OUT_DIM))[li] = a0;
    }
}

// ---------------- launch ----------------

extern "C" void kernel_launch(void* const* d_in, const int* in_sizes, int n_in,
                              void* d_out, int out_size, void* d_ws, size_t ws_size,
                              hipStream_t stream) {
    const float* x  = (const float*)d_in[0];
    const int*   ei = (const int*)d_in[1];
    const float* w  = (const float*)d_in[2];
    const float* W1 = (const float*)d_in[3];
    const float* b1 = (const float*)d_in[4];
    const float* W2 = (const float*)d_in[5];
    const float* b2 = (const float*)d_in[6];
    float* out = (float*)d_out;

    int N = in_sizes[0] / IN_DIM;       // 100000
    int E = in_sizes[2];                // 1600000
    const int* row = ei;
    const int* col = ei + E;

    char* base = (char*)d_ws;
    size_t off = 0;
    auto alloc = [&](size_t bytes) -> void* {
        void* p = base + off;
        off += (bytes + 255) & ~(size_t)255;
        return p;
    };
    unsigned long long* packed = (unsigned long long*)alloc((size_t)N * 8);
    float* dinv     = (float*)alloc((size_t)N * 4);
    int*   cnt      = (int*)  alloc((size_t)N * 4);
    int*   offsets  = (int*)  alloc((size_t)(N + 1) * 4);
    int*   cursors  = (int*)  alloc((size_t)N * 4);
    int*   bsum     = (int*)  alloc((size_t)1024 * 4);
    int2*  csc      = (int2*) alloc((size_t)E * 8);
    float* h        = (float*)alloc((size_t)N * HID_DIM * 4);
    float* hagg     = (float*)alloc((size_t)N * HID_DIM * 4);
    unsigned short* wt1h = (unsigned short*)alloc((size_t)IN_DIM * HID_DIM * 2);
    unsigned short* wt1l = (unsigned short*)alloc((size_t)IN_DIM * HID_DIM * 2);
    unsigned short* wt2h = (unsigned short*)alloc((size_t)HID_DIM * OUT_DIM * 2);
    unsigned short* wt2l = (unsigned short*)alloc((size_t)HID_DIM * OUT_DIM * 2);

    int gN = (N + 255) / 256;
    int gE = (E + 255) / 256;
    int gGemm = (N + 127) / 128;
    int gAgg = (N + 3) / 4;
    int nbScan = (N + 1023) / 1024;

    wsplit_kernel<<<(IN_DIM * HID_DIM + 255) / 256, 256, 0, stream>>>(
        W1, wt1h, wt1l, IN_DIM, HID_DIM);
    wsplit_kernel<<<(HID_DIM * OUT_DIM + 255) / 256, 256, 0, stream>>>(
        W2, wt2h, wt2l, HID_DIM, OUT_DIM);
    init_kernel<<<gN, 256, 0, stream>>>(packed, N);
    deg_cnt_kernel<<<gE, 256, 0, stream>>>(col, w, packed, E);
    dinv_kernel<<<gN, 256, 0, stream>>>(packed, dinv, cnt, N);
    scan1_kernel<<<nbScan, 256, 0, stream>>>(cnt, bsum, N);
    scan2_kernel<<<1, 1024, 0, stream>>>(bsum, offsets + N, nbScan);
    scan3_kernel<<<nbScan, 256, 0, stream>>>(cnt, bsum, offsets, cursors, N);
    fill_csc_kernel<<<gE, 256, 0, stream>>>(row, col, w, dinv, cursors, csc, E);
    gemm_mfma_kernel<IN_DIM, HID_DIM><<<gGemm, 256, 0, stream>>>(x, wt1h, wt1l, h, N);
    agg1_kernel<<<gAgg, 256, 0, stream>>>(h, dinv, offsets, csc, b1, hagg, N);
    gemm_mfma_kernel<HID_DIM, OUT_DIM><<<gGemm, 256, 0, stream>>>(hagg, wt2h, wt2l, h, N);
    agg2_kernel<<<gAgg, 256, 0, stream>>>(h, dinv, offsets, csc, b2, out, N);
}

// Round 6
// 493.809 us; speedup vs baseline: 2.0834x; 1.1127x over previous
//
#include <hip/hip_runtime.h>
#include <hip/hip_fp16.h>

#define IN_DIM 256
#define HID_DIM 128
#define OUT_DIM 64

typedef short s8v __attribute__((ext_vector_type(8)));
typedef float f32x4 __attribute__((ext_vector_type(4)));

// ---------------- bf16 split helpers ----------------

__device__ __forceinline__ unsigned short bf16_rne(float f) {
    unsigned int u = __float_as_uint(f);
    u += 0x7FFFu + ((u >> 16) & 1u);
    return (unsigned short)(u >> 16);
}
__device__ __forceinline__ float bfbits_to_f(unsigned short h) {
    return __uint_as_float(((unsigned int)h) << 16);
}
__device__ __forceinline__ void cvt_split4(float4 f, uint2& hv, uint2& lv) {
    unsigned short h0 = bf16_rne(f.x), h1 = bf16_rne(f.y);
    unsigned short h2 = bf16_rne(f.z), h3 = bf16_rne(f.w);
    unsigned short l0 = bf16_rne(f.x - bfbits_to_f(h0));
    unsigned short l1 = bf16_rne(f.y - bfbits_to_f(h1));
    unsigned short l2 = bf16_rne(f.z - bfbits_to_f(h2));
    unsigned short l3 = bf16_rne(f.w - bfbits_to_f(h3));
    hv.x = (unsigned int)h0 | ((unsigned int)h1 << 16);
    hv.y = (unsigned int)h2 | ((unsigned int)h3 << 16);
    lv.x = (unsigned int)l0 | ((unsigned int)l1 << 16);
    lv.y = (unsigned int)l2 | ((unsigned int)l3 << 16);
}

__global__ __launch_bounds__(256) void wsplit_kernel(const float* __restrict__ W,
        unsigned short* __restrict__ wth, unsigned short* __restrict__ wtl,
        int K, int NCOL) {
    int idx = blockIdx.x * 256 + threadIdx.x;
    if (idx < K * NCOL) {
        int k = idx / NCOL, nn = idx % NCOL;
        float f = W[idx];
        unsigned short h = bf16_rne(f);
        unsigned short l = bf16_rne(f - bfbits_to_f(h));
        wth[nn * K + k] = h;
        wtl[nn * K + k] = l;
    }
}

// ---------------- preprocessing ----------------
// packed[i]: bits [63:40] = edge count, bits [39:0] = fixed-point (2^-24) sum of w.

#define FPSCALE 16777216.0f
#define FPMASK  ((1ULL << 40) - 1)

__global__ __launch_bounds__(256) void init_kernel(unsigned long long* packed, int n) {
    int i = blockIdx.x * 256 + threadIdx.x;
    if (i < n) packed[i] = (1ULL << 24);      // deg = 1.0, cnt = 0
}

__global__ __launch_bounds__(256) void deg_cnt_kernel(const int* __restrict__ col,
        const float* __restrict__ w, unsigned long long* packed, int e) {
    int i = blockIdx.x * 256 + threadIdx.x;
    if (i < e) {
        unsigned long long v = (1ULL << 40) |
            (unsigned long long)(w[i] * FPSCALE + 0.5f);
        atomicAdd(&packed[col[i]], v);
    }
}

__global__ __launch_bounds__(256) void dinv_kernel(const unsigned long long* __restrict__ packed,
        float* __restrict__ dinv, int* __restrict__ cnt, int n) {
    int i = blockIdx.x * 256 + threadIdx.x;
    if (i < n) {
        unsigned long long p = packed[i];
        float d = (float)(p & FPMASK) * (1.0f / FPSCALE);
        dinv[i] = d > 0.0f ? rsqrtf(d) : 0.0f;
        cnt[i] = (int)(p >> 40);
    }
}

// ---- hierarchical exclusive scan ----

__global__ __launch_bounds__(256) void scan1_kernel(const int* __restrict__ cnt,
        int* __restrict__ bsum, int n) {
    int t = threadIdx.x;
    int base = blockIdx.x * 1024 + t * 4;
    int s = 0;
    if (base + 3 < n) {
        int4 v = *(const int4*)(cnt + base);
        s = v.x + v.y + v.z + v.w;
    } else {
        for (int i = 0; i < 4; i++) if (base + i < n) s += cnt[base + i];
    }
    __shared__ int sm[256];
    sm[t] = s;
    __syncthreads();
    for (int d = 1; d < 256; d <<= 1) {
        int v = (t >= d) ? sm[t - d] : 0;
        __syncthreads();
        sm[t] += v;
        __syncthreads();
    }
    if (t == 255) bsum[blockIdx.x] = sm[255];
}

__global__ __launch_bounds__(1024) void scan2_kernel(int* bsum, int* total_out, int nb) {
    __shared__ int sm[1024];
    int t = threadIdx.x;
    int v = (t < nb) ? bsum[t] : 0;
    sm[t] = v;
    __syncthreads();
    for (int d = 1; d < 1024; d <<= 1) {
        int u = (t >= d) ? sm[t - d] : 0;
        __syncthreads();
        sm[t] += u;
        __syncthreads();
    }
    int ex = (t == 0) ? 0 : sm[t - 1];
    if (t < nb) bsum[t] = ex;
    if (t == nb - 1) *total_out = sm[t];
}

__global__ __launch_bounds__(256) void scan3_kernel(const int* __restrict__ cnt,
        const int* __restrict__ bsum, int* __restrict__ offsets,
        int* __restrict__ cursors, int n) {
    int t = threadIdx.x;
    int base = blockIdx.x * 1024 + t * 4;
    int a[4] = {0, 0, 0, 0};
    if (base + 3 < n) {
        int4 v = *(const int4*)(cnt + base);
        a[0] = v.x; a[1] = v.y; a[2] = v.z; a[3] = v.w;
    } else {
        for (int i = 0; i < 4; i++) if (base + i < n) a[i] = cnt[base + i];
    }
    int s = a[0] + a[1] + a[2] + a[3];
    __shared__ int sm[256];
    sm[t] = s;
    __syncthreads();
    for (int d = 1; d < 256; d <<= 1) {
        int u = (t >= d) ? sm[t - d] : 0;
        __syncthreads();
        sm[t] += u;
        __syncthreads();
    }
    int pre = bsum[blockIdx.x] + ((t == 0) ? 0 : sm[t - 1]);
    int o0 = pre, o1 = o0 + a[0], o2 = o1 + a[1], o3 = o2 + a[2];
    if (base + 3 < n) {
        *(int4*)(offsets + base) = make_int4(o0, o1, o2, o3);
        *(int4*)(cursors + base) = make_int4(o0, o1, o2, o3);
    } else {
        int o[4] = {o0, o1, o2, o3};
        for (int i = 0; i < 4; i++) if (base + i < n) {
            offsets[base + i] = o[i];
            cursors[base + i] = o[i];
        }
    }
}

__global__ __launch_bounds__(256) void fill_csc_kernel(const int* __restrict__ row,
        const int* __restrict__ col, const float* __restrict__ w,
        const float* __restrict__ dinv, int* cursors,
        int2* __restrict__ csc, int e) {
    int i = blockIdx.x * 256 + threadIdx.x;
    if (i < e) {
        int r = row[i], c = col[i];
        float nrm = dinv[r] * w[i] * dinv[c];
        int p = atomicAdd(&cursors[c], 1);
        csc[p] = make_int2(r, __float_as_int(nrm));
    }
}

// ---------------- MFMA split-bf16 GEMM (fp16 output) ----------------

template<int K, int NCOL>
__global__ __launch_bounds__(256) void gemm_mfma_kernel(
        const float* __restrict__ x, const unsigned short* __restrict__ wth,
        const unsigned short* __restrict__ wtl, __half* __restrict__ out, int n) {
    constexpr int NT = NCOL / 16;
    constexpr int NCH = K / 32;
    __shared__ unsigned short sAh[128 * 40];
    __shared__ unsigned short sAl[128 * 40];
    __shared__ unsigned short sBh[NCOL * 40];
    __shared__ unsigned short sBl[NCOL * 40];

    int t = threadIdx.x;
    int wave = t >> 6, lane = t & 63, quad = lane >> 4, r16 = lane & 15;
    long rowBase = (long)blockIdx.x * 128;

    f32x4 acc[2][NT];
#pragma unroll
    for (int mi = 0; mi < 2; mi++)
#pragma unroll
        for (int nt = 0; nt < NT; nt++) acc[mi][nt] = (f32x4)0.0f;

    int srow = t >> 1;
    int skseg = (t & 1) * 16;
    long sgr = rowBase + srow; if (sgr > n - 1) sgr = n - 1;
    const float* xrow = x + sgr * K + skseg;

    for (int kc = 0; kc < NCH; kc++) {
        const float4* xs = (const float4*)(xrow + kc * 32);
        float4 f0 = xs[0], f1 = xs[1], f2 = xs[2], f3 = xs[3];
        uint2 h0, l0, h1, l1, h2, l2, h3, l3;
        cvt_split4(f0, h0, l0); cvt_split4(f1, h1, l1);
        cvt_split4(f2, h2, l2); cvt_split4(f3, h3, l3);
        *(uint4*)(sAh + srow * 40 + skseg)     = make_uint4(h0.x, h0.y, h1.x, h1.y);
        *(uint4*)(sAh + srow * 40 + skseg + 8) = make_uint4(h2.x, h2.y, h3.x, h3.y);
        *(uint4*)(sAl + srow * 40 + skseg)     = make_uint4(l0.x, l0.y, l1.x, l1.y);
        *(uint4*)(sAl + srow * 40 + skseg + 8) = make_uint4(l2.x, l2.y, l3.x, l3.y);
        for (int c = t; c < NCOL * 4; c += 256) {
            int nn = c >> 2, ks = (c & 3) * 8;
            *(uint4*)(sBh + nn * 40 + ks) = *(const uint4*)(wth + nn * K + kc * 32 + ks);
            *(uint4*)(sBl + nn * 40 + ks) = *(const uint4*)(wtl + nn * K + kc * 32 + ks);
        }
        __syncthreads();
        const unsigned short* pa  = sAh + (wave * 32 + r16) * 40 + quad * 8;
        const unsigned short* pal = sAl + (wave * 32 + r16) * 40 + quad * 8;
        s8v ah0 = *(const s8v*)pa;
        s8v ah1 = *(const s8v*)(pa + 16 * 40);
        s8v al0 = *(const s8v*)pal;
        s8v al1 = *(const s8v*)(pal + 16 * 40);
#pragma unroll
        for (int nt = 0; nt < NT; nt++) {
            const unsigned short* pb  = sBh + (nt * 16 + r16) * 40 + quad * 8;
            const unsigned short* pbl = sBl + (nt * 16 + r16) * 40 + quad * 8;
            s8v bh = *(const s8v*)pb;
            s8v bl = *(const s8v*)pbl;
            acc[0][nt] = __builtin_amdgcn_mfma_f32_16x16x32_bf16(ah0, bh, acc[0][nt], 0, 0, 0);
            acc[0][nt] = __builtin_amdgcn_mfma_f32_16x16x32_bf16(al0, bh, acc[0][nt], 0, 0, 0);
            acc[0][nt] = __builtin_amdgcn_mfma_f32_16x16x32_bf16(ah0, bl, acc[0][nt], 0, 0, 0);
            acc[1][nt] = __builtin_amdgcn_mfma_f32_16x16x32_bf16(ah1, bh, acc[1][nt], 0, 0, 0);
            acc[1][nt] = __builtin_amdgcn_mfma_f32_16x16x32_bf16(al1, bh, acc[1][nt], 0, 0, 0);
            acc[1][nt] = __builtin_amdgcn_mfma_f32_16x16x32_bf16(ah1, bl, acc[1][nt], 0, 0, 0);
        }
        __syncthreads();
    }
#pragma unroll
    for (int mi = 0; mi < 2; mi++) {
        long gr0 = rowBase + wave * 32 + mi * 16 + quad * 4;
#pragma unroll
        for (int nt = 0; nt < NT; nt++) {
            f32x4 d = acc[mi][nt];
#pragma unroll
            for (int i = 0; i < 4; i++) {
                long gr = gr0 + i;
                if (gr < n) out[gr * NCOL + nt * 16 + r16] = __float2half(d[i]);
            }
        }
    }
}

// ---------------- fp16 gather accumulate helpers ----------------

__device__ __forceinline__ void acc8(float* a, uint4 raw, float w) {
    __half2* hp = (__half2*)&raw;
    float2 f0 = __half22float2(hp[0]);
    float2 f1 = __half22float2(hp[1]);
    float2 f2 = __half22float2(hp[2]);
    float2 f3 = __half22float2(hp[3]);
    a[0] += w * f0.x; a[1] += w * f0.y; a[2] += w * f1.x; a[3] += w * f1.y;
    a[4] += w * f2.x; a[5] += w * f2.y; a[6] += w * f3.x; a[7] += w * f3.y;
}

__device__ __forceinline__ void acc4h(float* a, uint2 raw, float w) {
    __half2* hp = (__half2*)&raw;
    float2 f0 = __half22float2(hp[0]);
    float2 f1 = __half22float2(hp[1]);
    a[0] += w * f0.x; a[1] += w * f0.y; a[2] += w * f1.x; a[3] += w * f1.y;
}

// ---------------- aggregation layer 1 (D=128 fp16 in, fp32 out, +bias, relu) ----
// 16 lanes x half8 (16B) cover the row; 4 edge-streams x 2-unroll = 8 gathers in flight.

__global__ __launch_bounds__(256) void agg1_kernel(const __half* __restrict__ h,
        const float* __restrict__ dinv, const int* __restrict__ offsets,
        const int2* __restrict__ csc, const float* __restrict__ b,
        float* __restrict__ out, int n) {
    int t = threadIdx.x;
    int lane = t & 63;
    int strm = lane >> 4;            // 0..3
    int li = lane & 15;              // half8 index in row (16*8 = 128 dims)
    int node = blockIdx.x * 4 + (t >> 6);
    if (node >= n) return;

    float a0[8] = {0,0,0,0,0,0,0,0};
    float a1[8] = {0,0,0,0,0,0,0,0};
    int s = offsets[node], e = offsets[node + 1];

    if (strm == 0) {
        float di = dinv[node];
        uint4 raw = ((const uint4*)(h + (long)node * HID_DIM))[li];
        acc8(a0, raw, di * di);
    }

    int p = s + strm;
    for (; p + 4 < e; p += 8) {
        int2 e0 = csc[p], e1 = csc[p + 4];
        uint4 r0 = ((const uint4*)(h + (long)e0.x * HID_DIM))[li];
        uint4 r1 = ((const uint4*)(h + (long)e1.x * HID_DIM))[li];
        acc8(a0, r0, __int_as_float(e0.y));
        acc8(a1, r1, __int_as_float(e1.y));
    }
    if (p < e) {
        int2 e0 = csc[p];
        uint4 r0 = ((const uint4*)(h + (long)e0.x * HID_DIM))[li];
        acc8(a0, r0, __int_as_float(e0.y));
    }
#pragma unroll
    for (int j = 0; j < 8; j++) a0[j] += a1[j];
#pragma unroll
    for (int j = 0; j < 8; j++) a0[j] += __shfl_down(a0[j], 32);
#pragma unroll
    for (int j = 0; j < 8; j++) a0[j] += __shfl_down(a0[j], 16);
    if (strm == 0) {
        float4 bv0 = ((const float4*)b)[li * 2];
        float4 bv1 = ((const float4*)b)[li * 2 + 1];
        float4 o0 = make_float4(fmaxf(a0[0] + bv0.x, 0.f), fmaxf(a0[1] + bv0.y, 0.f),
                                fmaxf(a0[2] + bv0.z, 0.f), fmaxf(a0[3] + bv0.w, 0.f));
        float4 o1 = make_float4(fmaxf(a0[4] + bv1.x, 0.f), fmaxf(a0[5] + bv1.y, 0.f),
                                fmaxf(a0[6] + bv1.z, 0.f), fmaxf(a0[7] + bv1.w, 0.f));
        float4* dst = (float4*)(out + (long)node * HID_DIM);
        dst[li * 2] = o0;
        dst[li * 2 + 1] = o1;
    }
}

// ---------------- aggregation layer 2 (D=64 fp16 in, fp32 out, +bias) ----------
// 16 lanes x half4 (8B) cover the row; 4 edge-streams x 2-unroll = 8 gathers in flight.

__global__ __launch_bounds__(256) void agg2_kernel(const __half* __restrict__ h,
        const float* __restrict__ dinv, const int* __restrict__ offsets,
        const int2* __restrict__ csc, const float* __restrict__ b,
        float* __restrict__ out, int n) {
    int t = threadIdx.x;
    int lane = t & 63;
    int strm = lane >> 4;            // 0..3
    int li = lane & 15;              // half4 index in row (16*4 = 64 dims)
    int node = blockIdx.x * 4 + (t >> 6);
    if (node >= n) return;

    float a0[4] = {0,0,0,0};
    float a1[4] = {0,0,0,0};
    int s = offsets[node], e = offsets[node + 1];

    if (strm == 0) {
        float di = dinv[node];
        uint2 raw = ((const uint2*)(h + (long)node * OUT_DIM))[li];
        acc4h(a0, raw, di * di);
    }

    int p = s + strm;
    for (; p + 4 < e; p += 8) {
        int2 e0 = csc[p], e1 = csc[p + 4];
        uint2 r0 = ((const uint2*)(h + (long)e0.x * OUT_DIM))[li];
        uint2 r1 = ((const uint2*)(h + (long)e1.x * OUT_DIM))[li];
        acc4h(a0, r0, __int_as_float(e0.y));
        acc4h(a1, r1, __int_as_float(e1.y));
    }
    if (p < e) {
        int2 e0 = csc[p];
        uint2 r0 = ((const uint2*)(h + (long)e0.x * OUT_DIM))[li];
        acc4h(a0, r0, __int_as_float(e0.y));
    }
#pragma unroll
    for (int j = 0; j < 4; j++) a0[j] += a1[j];
#pragma unroll
    for (int j = 0; j < 4; j++) a0[j] += __shfl_down(a0[j], 32);
#pragma unroll
    for (int j = 0; j < 4; j++) a0[j] += __shfl_down(a0[j], 16);
    if (strm == 0) {
        float4 bv = ((const float4*)b)[li];
        ((float4*)(out + (long)node * OUT_DIM))[li] =
            make_float4(a0[0] + bv.x, a0[1] + bv.y, a0[2] + bv.z, a0[3] + bv.w);
    }
}

// ---------------- launch ----------------

extern "C" void kernel_launch(void* const* d_in, const int* in_sizes, int n_in,
                              void* d_out, int out_size, void* d_ws, size_t ws_size,
                              hipStream_t stream) {
    const float* x  = (const float*)d_in[0];
    const int*   ei = (const int*)d_in[1];
    const float* w  = (const float*)d_in[2];
    const float* W1 = (const float*)d_in[3];
    const float* b1 = (const float*)d_in[4];
    const float* W2 = (const float*)d_in[5];
    const float* b2 = (const float*)d_in[6];
    float* out = (float*)d_out;

    int N = in_sizes[0] / IN_DIM;       // 100000
    int E = in_sizes[2];                // 1600000
    const int* row = ei;
    const int* col = ei + E;

    char* base = (char*)d_ws;
    size_t off = 0;
    auto alloc = [&](size_t bytes) -> void* {
        void* p = base + off;
        off += (bytes + 255) & ~(size_t)255;
        return p;
    };
    unsigned long long* packed = (unsigned long long*)alloc((size_t)N * 8);
    float* dinv     = (float*)alloc((size_t)N * 4);
    int*   cnt      = (int*)  alloc((size_t)N * 4);
    int*   offsets  = (int*)  alloc((size_t)(N + 1) * 4);
    int*   cursors  = (int*)  alloc((size_t)N * 4);
    int*   bsum     = (int*)  alloc((size_t)1024 * 4);
    int2*  csc      = (int2*) alloc((size_t)E * 8);
    __half* h       = (__half*)alloc((size_t)N * HID_DIM * 2);  // fp16; reused for h2
    float* hagg     = (float*)alloc((size_t)N * HID_DIM * 4);
    unsigned short* wt1h = (unsigned short*)alloc((size_t)IN_DIM * HID_DIM * 2);
    unsigned short* wt1l = (unsigned short*)alloc((size_t)IN_DIM * HID_DIM * 2);
    unsigned short* wt2h = (unsigned short*)alloc((size_t)HID_DIM * OUT_DIM * 2);
    unsigned short* wt2l = (unsigned short*)alloc((size_t)HID_DIM * OUT_DIM * 2);

    int gN = (N + 255) / 256;
    int gE = (E + 255) / 256;
    int gGemm = (N + 127) / 128;
    int gAgg = (N + 3) / 4;
    int nbScan = (N + 1023) / 1024;

    wsplit_kernel<<<(IN_DIM * HID_DIM + 255) / 256, 256, 0, stream>>>(
        W1, wt1h, wt1l, IN_DIM, HID_DIM);
    wsplit_kernel<<<(HID_DIM * OUT_DIM + 255) / 256, 256, 0, stream>>>(
        W2, wt2h, wt2l, HID_DIM, OUT_DIM);
    init_kernel<<<gN, 256, 0, stream>>>(packed, N);
    deg_cnt_kernel<<<gE, 256, 0, stream>>>(col, w, packed, E);
    dinv_kernel<<<gN, 256, 0, stream>>>(packed, dinv, cnt, N);
    scan1_kernel<<<nbScan, 256, 0, stream>>>(cnt, bsum, N);
    scan2_kernel<<<1, 1024, 0, stream>>>(bsum, offsets + N, nbScan);
    scan3_kernel<<<nbScan, 256, 0, stream>>>(cnt, bsum, offsets, cursors, N);
    fill_csc_kernel<<<gE, 256, 0, stream>>>(row, col, w, dinv, cursors, csc, E);
    gemm_mfma_kernel<IN_DIM, HID_DIM><<<gGemm, 256, 0, stream>>>(x, wt1h, wt1l, h, N);
    agg1_kernel<<<gAgg, 256, 0, stream>>>(h, dinv, offsets, csc, b1, hagg, N);
    gemm_mfma_kernel<HID_DIM, OUT_DIM><<<gGemm, 256, 0, stream>>>(hagg, wt2h, wt2l, h, N);
    agg2_kernel<<<gAgg, 256, 0, stream>>>(h, dinv, offsets, csc, b2, out, N);
}

// Round 7
// 474.552 us; speedup vs baseline: 2.1679x; 1.0406x over previous
//
#include <hip/hip_runtime.h>
#include <hip/hip_fp16.h>

#define IN_DIM 256
#define HID_DIM 128
#define OUT_DIM 64

typedef short s8v __attribute__((ext_vector_type(8)));
typedef float f32x4 __attribute__((ext_vector_type(4)));

// ---------------- bf16 split helpers ----------------

__device__ __forceinline__ unsigned short bf16_rne(float f) {
    unsigned int u = __float_as_uint(f);
    u += 0x7FFFu + ((u >> 16) & 1u);
    return (unsigned short)(u >> 16);
}
__device__ __forceinline__ float bfbits_to_f(unsigned short h) {
    return __uint_as_float(((unsigned int)h) << 16);
}
__device__ __forceinline__ void cvt_split4(float4 f, uint2& hv, uint2& lv) {
    unsigned short h0 = bf16_rne(f.x), h1 = bf16_rne(f.y);
    unsigned short h2 = bf16_rne(f.z), h3 = bf16_rne(f.w);
    unsigned short l0 = bf16_rne(f.x - bfbits_to_f(h0));
    unsigned short l1 = bf16_rne(f.y - bfbits_to_f(h1));
    unsigned short l2 = bf16_rne(f.z - bfbits_to_f(h2));
    unsigned short l3 = bf16_rne(f.w - bfbits_to_f(h3));
    hv.x = (unsigned int)h0 | ((unsigned int)h1 << 16);
    hv.y = (unsigned int)h2 | ((unsigned int)h3 << 16);
    lv.x = (unsigned int)l0 | ((unsigned int)l1 << 16);
    lv.y = (unsigned int)l2 | ((unsigned int)l3 << 16);
}

__global__ __launch_bounds__(256) void wsplit_kernel(const float* __restrict__ W,
        unsigned short* __restrict__ wth, unsigned short* __restrict__ wtl,
        int K, int NCOL) {
    int idx = blockIdx.x * 256 + threadIdx.x;
    if (idx < K * NCOL) {
        int k = idx / NCOL, nn = idx % NCOL;
        float f = W[idx];
        unsigned short h = bf16_rne(f);
        unsigned short l = bf16_rne(f - bfbits_to_f(h));
        wth[nn * K + k] = h;
        wtl[nn * K + k] = l;
    }
}

// ---------------- preprocessing ----------------
// packed[i]: bits [63:40] = edge count, bits [39:0] = fixed-point (2^-24) sum of w.

#define FPSCALE 16777216.0f
#define FPMASK  ((1ULL << 40) - 1)

__global__ __launch_bounds__(256) void init_kernel(unsigned long long* packed, int n) {
    int i = blockIdx.x * 256 + threadIdx.x;
    if (i < n) packed[i] = (1ULL << 24);      // deg = 1.0 (self-loop), cnt = 0
}

// One u64 atomic per edge; the RETURN VALUE's cnt field is this edge's
// arrival index at its destination -> deterministic CSC slot later (no 2nd atomic).
__global__ __launch_bounds__(256) void deg_cnt_kernel(const int* __restrict__ col,
        const float* __restrict__ w, unsigned long long* packed,
        int* __restrict__ arr, int e) {
    int i = blockIdx.x * 256 + threadIdx.x;
    if (i < e) {
        unsigned long long v = (1ULL << 40) |
            (unsigned long long)(w[i] * FPSCALE + 0.5f);
        unsigned long long old = atomicAdd(&packed[col[i]], v);
        arr[i] = (int)(old >> 40);
    }
}

__global__ __launch_bounds__(256) void dinv_kernel(const unsigned long long* __restrict__ packed,
        float* __restrict__ dinv, int* __restrict__ cnt, int n) {
    int i = blockIdx.x * 256 + threadIdx.x;
    if (i < n) {
        unsigned long long p = packed[i];
        float d = (float)(p & FPMASK) * (1.0f / FPSCALE);
        dinv[i] = d > 0.0f ? rsqrtf(d) : 0.0f;
        cnt[i] = (int)(p >> 40);
    }
}

// ---- hierarchical exclusive scan ----

__global__ __launch_bounds__(256) void scan1_kernel(const int* __restrict__ cnt,
        int* __restrict__ bsum, int n) {
    int t = threadIdx.x;
    int base = blockIdx.x * 1024 + t * 4;
    int s = 0;
    if (base + 3 < n) {
        int4 v = *(const int4*)(cnt + base);
        s = v.x + v.y + v.z + v.w;
    } else {
        for (int i = 0; i < 4; i++) if (base + i < n) s += cnt[base + i];
    }
    __shared__ int sm[256];
    sm[t] = s;
    __syncthreads();
    for (int d = 1; d < 256; d <<= 1) {
        int v = (t >= d) ? sm[t - d] : 0;
        __syncthreads();
        sm[t] += v;
        __syncthreads();
    }
    if (t == 255) bsum[blockIdx.x] = sm[255];
}

__global__ __launch_bounds__(1024) void scan2_kernel(int* bsum, int* total_out, int nb) {
    __shared__ int sm[1024];
    int t = threadIdx.x;
    int v = (t < nb) ? bsum[t] : 0;
    sm[t] = v;
    __syncthreads();
    for (int d = 1; d < 1024; d <<= 1) {
        int u = (t >= d) ? sm[t - d] : 0;
        __syncthreads();
        sm[t] += u;
        __syncthreads();
    }
    int ex = (t == 0) ? 0 : sm[t - 1];
    if (t < nb) bsum[t] = ex;
    if (t == nb - 1) *total_out = sm[t];
}

__global__ __launch_bounds__(256) void scan3_kernel(const int* __restrict__ cnt,
        const int* __restrict__ bsum, int* __restrict__ offsets, int n) {
    int t = threadIdx.x;
    int base = blockIdx.x * 1024 + t * 4;
    int a[4] = {0, 0, 0, 0};
    if (base + 3 < n) {
        int4 v = *(const int4*)(cnt + base);
        a[0] = v.x; a[1] = v.y; a[2] = v.z; a[3] = v.w;
    } else {
        for (int i = 0; i < 4; i++) if (base + i < n) a[i] = cnt[base + i];
    }
    int s = a[0] + a[1] + a[2] + a[3];
    __shared__ int sm[256];
    sm[t] = s;
    __syncthreads();
    for (int d = 1; d < 256; d <<= 1) {
        int u = (t >= d) ? sm[t - d] : 0;
        __syncthreads();
        sm[t] += u;
        __syncthreads();
    }
    int pre = bsum[blockIdx.x] + ((t == 0) ? 0 : sm[t - 1]);
    int o0 = pre, o1 = o0 + a[0], o2 = o1 + a[1], o3 = o2 + a[2];
    if (base + 3 < n) {
        *(int4*)(offsets + base) = make_int4(o0, o1, o2, o3);
    } else {
        int o[4] = {o0, o1, o2, o3};
        for (int i = 0; i < 4; i++) if (base + i < n) offsets[base + i] = o[i];
    }
}

// CSC entry: int2{ src_row, float_bits(w) } — dinv folded elsewhere.
// No atomic: slot = offsets[col] + arrival index from deg_cnt.

__global__ __launch_bounds__(256) void fill_csc_kernel(const int* __restrict__ row,
        const int* __restrict__ col, const float* __restrict__ w,
        const int* __restrict__ offsets, const int* __restrict__ arr,
        int2* __restrict__ csc, int e) {
    int i = blockIdx.x * 256 + threadIdx.x;
    if (i < e) {
        int c = col[i];
        int p = offsets[c] + arr[i];
        csc[p] = make_int2(row[i], __float_as_int(w[i]));
    }
}

// ---------------- MFMA split-bf16 GEMM (fp16 output, row-scaled by dinv) ------

template<int K, int NCOL>
__global__ __launch_bounds__(256) void gemm_mfma_kernel(
        const float* __restrict__ x, const unsigned short* __restrict__ wth,
        const unsigned short* __restrict__ wtl, const float* __restrict__ dinv,
        __half* __restrict__ out, int n) {
    constexpr int NT = NCOL / 16;
    constexpr int NCH = K / 32;
    __shared__ unsigned short sAh[128 * 40];
    __shared__ unsigned short sAl[128 * 40];
    __shared__ unsigned short sBh[NCOL * 40];
    __shared__ unsigned short sBl[NCOL * 40];

    int t = threadIdx.x;
    int wave = t >> 6, lane = t & 63, quad = lane >> 4, r16 = lane & 15;
    long rowBase = (long)blockIdx.x * 128;

    f32x4 acc[2][NT];
#pragma unroll
    for (int mi = 0; mi < 2; mi++)
#pragma unroll
        for (int nt = 0; nt < NT; nt++) acc[mi][nt] = (f32x4)0.0f;

    int srow = t >> 1;
    int skseg = (t & 1) * 16;
    long sgr = rowBase + srow; if (sgr > n - 1) sgr = n - 1;
    const float* xrow = x + sgr * K + skseg;

    for (int kc = 0; kc < NCH; kc++) {
        const float4* xs = (const float4*)(xrow + kc * 32);
        float4 f0 = xs[0], f1 = xs[1], f2 = xs[2], f3 = xs[3];
        uint2 h0, l0, h1, l1, h2, l2, h3, l3;
        cvt_split4(f0, h0, l0); cvt_split4(f1, h1, l1);
        cvt_split4(f2, h2, l2); cvt_split4(f3, h3, l3);
        *(uint4*)(sAh + srow * 40 + skseg)     = make_uint4(h0.x, h0.y, h1.x, h1.y);
        *(uint4*)(sAh + srow * 40 + skseg + 8) = make_uint4(h2.x, h2.y, h3.x, h3.y);
        *(uint4*)(sAl + srow * 40 + skseg)     = make_uint4(l0.x, l0.y, l1.x, l1.y);
        *(uint4*)(sAl + srow * 40 + skseg + 8) = make_uint4(l2.x, l2.y, l3.x, l3.y);
        for (int c = t; c < NCOL * 4; c += 256) {
            int nn = c >> 2, ks = (c & 3) * 8;
            *(uint4*)(sBh + nn * 40 + ks) = *(const uint4*)(wth + nn * K + kc * 32 + ks);
            *(uint4*)(sBl + nn * 40 + ks) = *(const uint4*)(wtl + nn * K + kc * 32 + ks);
        }
        __syncthreads();
        const unsigned short* pa  = sAh + (wave * 32 + r16) * 40 + quad * 8;
        const unsigned short* pal = sAl + (wave * 32 + r16) * 40 + quad * 8;
        s8v ah0 = *(const s8v*)pa;
        s8v ah1 = *(const s8v*)(pa + 16 * 40);
        s8v al0 = *(const s8v*)pal;
        s8v al1 = *(const s8v*)(pal + 16 * 40);
#pragma unroll
        for (int nt = 0; nt < NT; nt++) {
            const unsigned short* pb  = sBh + (nt * 16 + r16) * 40 + quad * 8;
            const unsigned short* pbl = sBl + (nt * 16 + r16) * 40 + quad * 8;
            s8v bh = *(const s8v*)pb;
            s8v bl = *(const s8v*)pbl;
            acc[0][nt] = __builtin_amdgcn_mfma_f32_16x16x32_bf16(ah0, bh, acc[0][nt], 0, 0, 0);
            acc[0][nt] = __builtin_amdgcn_mfma_f32_16x16x32_bf16(al0, bh, acc[0][nt], 0, 0, 0);
            acc[0][nt] = __builtin_amdgcn_mfma_f32_16x16x32_bf16(ah0, bl, acc[0][nt], 0, 0, 0);
            acc[1][nt] = __builtin_amdgcn_mfma_f32_16x16x32_bf16(ah1, bh, acc[1][nt], 0, 0, 0);
            acc[1][nt] = __builtin_amdgcn_mfma_f32_16x16x32_bf16(al1, bh, acc[1][nt], 0, 0, 0);
            acc[1][nt] = __builtin_amdgcn_mfma_f32_16x16x32_bf16(ah1, bl, acc[1][nt], 0, 0, 0);
        }
        __syncthreads();
    }
#pragma unroll
    for (int mi = 0; mi < 2; mi++) {
        long gr0 = rowBase + wave * 32 + mi * 16 + quad * 4;
#pragma unroll
        for (int nt = 0; nt < NT; nt++) {
            f32x4 d = acc[mi][nt];
#pragma unroll
            for (int i = 0; i < 4; i++) {
                long gr = gr0 + i;
                if (gr < n) out[gr * NCOL + nt * 16 + r16] =
                    __float2half(d[i] * dinv[gr]);
            }
        }
    }
}

// ---------------- fp16 gather accumulate helpers ----------------

__device__ __forceinline__ void acc8(float* a, uint4 raw, float w) {
    __half2* hp = (__half2*)&raw;
    float2 f0 = __half22float2(hp[0]);
    float2 f1 = __half22float2(hp[1]);
    float2 f2 = __half22float2(hp[2]);
    float2 f3 = __half22float2(hp[3]);
    a[0] += w * f0.x; a[1] += w * f0.y; a[2] += w * f1.x; a[3] += w * f1.y;
    a[4] += w * f2.x; a[5] += w * f2.y; a[6] += w * f3.x; a[7] += w * f3.y;
}

__device__ __forceinline__ void acc4h(float* a, uint2 raw, float w) {
    __half2* hp = (__half2*)&raw;
    float2 f0 = __half22float2(hp[0]);
    float2 f1 = __half22float2(hp[1]);
    a[0] += w * f0.x; a[1] += w * f0.y; a[2] += w * f1.x; a[3] += w * f1.y;
}

// ---------------- aggregation layer 1 (D=128 fp16 in, fp32 out, +bias, relu) ----
// h' rows are pre-scaled by dinv[src]; edge weight is raw w; final scale dinv[node].

__global__ __launch_bounds__(256) void agg1_kernel(const __half* __restrict__ h,
        const float* __restrict__ dinv, const int* __restrict__ offsets,
        const int2* __restrict__ csc, const float* __restrict__ b,
        float* __restrict__ out, int n) {
    int t = threadIdx.x;
    int lane = t & 63;
    int strm = lane >> 4;            // 0..3
    int li = lane & 15;              // half8 index in row (16*8 = 128 dims)
    int node = blockIdx.x * 4 + (t >> 6);
    if (node >= n) return;

    float a0[8] = {0,0,0,0,0,0,0,0};
    float a1[8] = {0,0,0,0,0,0,0,0};
    int s = offsets[node], e = offsets[node + 1];

    if (strm == 0) {                 // self-loop: weight 1 * h'[node]
        uint4 raw = ((const uint4*)(h + (long)node * HID_DIM))[li];
        acc8(a0, raw, 1.0f);
    }

    int p = s + strm;
    for (; p + 4 < e; p += 8) {
        int2 e0 = csc[p], e1 = csc[p + 4];
        uint4 r0 = ((const uint4*)(h + (long)e0.x * HID_DIM))[li];
        uint4 r1 = ((const uint4*)(h + (long)e1.x * HID_DIM))[li];
        acc8(a0, r0, __int_as_float(e0.y));
        acc8(a1, r1, __int_as_float(e1.y));
    }
    if (p < e) {
        int2 e0 = csc[p];
        uint4 r0 = ((const uint4*)(h + (long)e0.x * HID_DIM))[li];
        acc8(a0, r0, __int_as_float(e0.y));
    }
#pragma unroll
    for (int j = 0; j < 8; j++) a0[j] += a1[j];
#pragma unroll
    for (int j = 0; j < 8; j++) a0[j] += __shfl_down(a0[j], 32);
#pragma unroll
    for (int j = 0; j < 8; j++) a0[j] += __shfl_down(a0[j], 16);
    if (strm == 0) {
        float di = dinv[node];
        float4 bv0 = ((const float4*)b)[li * 2];
        float4 bv1 = ((const float4*)b)[li * 2 + 1];
        float4 o0 = make_float4(fmaxf(di * a0[0] + bv0.x, 0.f), fmaxf(di * a0[1] + bv0.y, 0.f),
                                fmaxf(di * a0[2] + bv0.z, 0.f), fmaxf(di * a0[3] + bv0.w, 0.f));
        float4 o1 = make_float4(fmaxf(di * a0[4] + bv1.x, 0.f), fmaxf(di * a0[5] + bv1.y, 0.f),
                                fmaxf(di * a0[6] + bv1.z, 0.f), fmaxf(di * a0[7] + bv1.w, 0.f));
        float4* dst = (float4*)(out + (long)node * HID_DIM);
        dst[li * 2] = o0;
        dst[li * 2 + 1] = o1;
    }
}

// ---------------- aggregation layer 2 (D=64 fp16 in, fp32 out, +bias) ----------

__global__ __launch_bounds__(256) void agg2_kernel(const __half* __restrict__ h,
        const float* __restrict__ dinv, const int* __restrict__ offsets,
        const int2* __restrict__ csc, const float* __restrict__ b,
        float* __restrict__ out, int n) {
    int t = threadIdx.x;
    int lane = t & 63;
    int strm = lane >> 4;            // 0..3
    int li = lane & 15;              // half4 index in row (16*4 = 64 dims)
    int node = blockIdx.x * 4 + (t >> 6);
    if (node >= n) return;

    float a0[4] = {0,0,0,0};
    float a1[4] = {0,0,0,0};
    int s = offsets[node], e = offsets[node + 1];

    if (strm == 0) {
        uint2 raw = ((const uint2*)(h + (long)node * OUT_DIM))[li];
        acc4h(a0, raw, 1.0f);
    }

    int p = s + strm;
    for (; p + 4 < e; p += 8) {
        int2 e0 = csc[p], e1 = csc[p + 4];
        uint2 r0 = ((const uint2*)(h + (long)e0.x * OUT_DIM))[li];
        uint2 r1 = ((const uint2*)(h + (long)e1.x * OUT_DIM))[li];
        acc4h(a0, r0, __int_as_float(e0.y));
        acc4h(a1, r1, __int_as_float(e1.y));
    }
    if (p < e) {
        int2 e0 = csc[p];
        uint2 r0 = ((const uint2*)(h + (long)e0.x * OUT_DIM))[li];
        acc4h(a0, r0, __int_as_float(e0.y));
    }
#pragma unroll
    for (int j = 0; j < 4; j++) a0[j] += a1[j];
#pragma unroll
    for (int j = 0; j < 4; j++) a0[j] += __shfl_down(a0[j], 32);
#pragma unroll
    for (int j = 0; j < 4; j++) a0[j] += __shfl_down(a0[j], 16);
    if (strm == 0) {
        float di = dinv[node];
        float4 bv = ((const float4*)b)[li];
        ((float4*)(out + (long)node * OUT_DIM))[li] =
            make_float4(di * a0[0] + bv.x, di * a0[1] + bv.y,
                        di * a0[2] + bv.z, di * a0[3] + bv.w);
    }
}

// ---------------- launch ----------------

extern "C" void kernel_launch(void* const* d_in, const int* in_sizes, int n_in,
                              void* d_out, int out_size, void* d_ws, size_t ws_size,
                              hipStream_t stream) {
    const float* x  = (const float*)d_in[0];
    const int*   ei = (const int*)d_in[1];
    const float* w  = (const float*)d_in[2];
    const float* W1 = (const float*)d_in[3];
    const float* b1 = (const float*)d_in[4];
    const float* W2 = (const float*)d_in[5];
    const float* b2 = (const float*)d_in[6];
    float* out = (float*)d_out;

    int N = in_sizes[0] / IN_DIM;       // 100000
    int E = in_sizes[2];                // 1600000
    const int* row = ei;
    const int* col = ei + E;

    char* base = (char*)d_ws;
    size_t off = 0;
    auto alloc = [&](size_t bytes) -> void* {
        void* p = base + off;
        off += (bytes + 255) & ~(size_t)255;
        return p;
    };
    unsigned long long* packed = (unsigned long long*)alloc((size_t)N * 8);
    float* dinv     = (float*)alloc((size_t)N * 4);
    int*   cnt      = (int*)  alloc((size_t)N * 4);
    int*   offsets  = (int*)  alloc((size_t)(N + 1) * 4);
    int*   arr      = (int*)  alloc((size_t)E * 4);
    int*   bsum     = (int*)  alloc((size_t)1024 * 4);
    int2*  csc      = (int2*) alloc((size_t)E * 8);
    __half* h       = (__half*)alloc((size_t)N * HID_DIM * 2);  // fp16; reused for h2
    float* hagg     = (float*)alloc((size_t)N * HID_DIM * 4);
    unsigned short* wt1h = (unsigned short*)alloc((size_t)IN_DIM * HID_DIM * 2);
    unsigned short* wt1l = (unsigned short*)alloc((size_t)IN_DIM * HID_DIM * 2);
    unsigned short* wt2h = (unsigned short*)alloc((size_t)HID_DIM * OUT_DIM * 2);
    unsigned short* wt2l = (unsigned short*)alloc((size_t)HID_DIM * OUT_DIM * 2);

    int gN = (N + 255) / 256;
    int gE = (E + 255) / 256;
    int gGemm = (N + 127) / 128;
    int gAgg = (N + 3) / 4;
    int nbScan = (N + 1023) / 1024;

    wsplit_kernel<<<(IN_DIM * HID_DIM + 255) / 256, 256, 0, stream>>>(
        W1, wt1h, wt1l, IN_DIM, HID_DIM);
    wsplit_kernel<<<(HID_DIM * OUT_DIM + 255) / 256, 256, 0, stream>>>(
        W2, wt2h, wt2l, HID_DIM, OUT_DIM);
    init_kernel<<<gN, 256, 0, stream>>>(packed, N);
    deg_cnt_kernel<<<gE, 256, 0, stream>>>(col, w, packed, arr, E);
    dinv_kernel<<<gN, 256, 0, stream>>>(packed, dinv, cnt, N);
    scan1_kernel<<<nbScan, 256, 0, stream>>>(cnt, bsum, N);
    scan2_kernel<<<1, 1024, 0, stream>>>(bsum, offsets + N, nbScan);
    scan3_kernel<<<nbScan, 256, 0, stream>>>(cnt, bsum, offsets, N);
    fill_csc_kernel<<<gE, 256, 0, stream>>>(row, col, w, offsets, arr, csc, E);
    gemm_mfma_kernel<IN_DIM, HID_DIM><<<gGemm, 256, 0, stream>>>(x, wt1h, wt1l, dinv, h, N);
    agg1_kernel<<<gAgg, 256, 0, stream>>>(h, dinv, offsets, csc, b1, hagg, N);
    gemm_mfma_kernel<HID_DIM, OUT_DIM><<<gGemm, 256, 0, stream>>>(hagg, wt2h, wt2l, dinv, h, N);
    agg2_kernel<<<gAgg, 256, 0, stream>>>(h, dinv, offsets, csc, b2, out, N);
}